// Round 3
// baseline (8611.900 us; speedup 1.0000x reference)
//
#include <hip/hip_runtime.h>
#include <hip/hip_bf16.h>

typedef unsigned short u16;

#define DM 1024      // d_model
#define HM 4096      // ffn hidden
#define NHEADS 16
#define HD 64        // head dim
#define SQ 2048      // seq len
#define NBATCH 2
#define NTOK 4096    // NBATCH*SQ
#define QT 4         // q rows per attention block

#define NX  ((size_t)NTOK * DM)   // 4194304 (x / activations)
#define NW  ((size_t)DM * DM)     // 1048576 (wq/wk/wv/wo)
#define NW1 ((size_t)HM * DM)     // 4194304 (w1)
#define NW2 ((size_t)DM * HM)     // 4194304 (w2)

__device__ __forceinline__ float bits2f(unsigned int u) {
    union { unsigned int i; float f; } w; w.i = u << 16; return w.f;
}

// ---- probe: decide whether inputs are bf16 (flag=1) or fp32 (flag=0) ----
__global__ void probe_kernel(const u16* __restrict__ x, int* __restrict__ flag) {
    __shared__ int part[256];
    int tid = threadIdx.x;
    int cnt = 0;
    for (int i = tid; i < 4096; i += 256) {
        float v = bits2f(x[i]);
        float a = fabsf(v);
        if (v == v && a > 1e-5f && a < 100.0f) cnt++;
    }
    part[tid] = cnt;
    __syncthreads();
    if (tid == 0) {
        int tot = 0;
        for (int i = 0; i < 256; i++) tot += part[i];
        // bf16 buffer -> ~4096 plausible; fp32 buffer -> ~2250
        *flag = (tot > 3300) ? 1 : 0;
    }
}

// ---- convert any input tensor to fp32 based on flag ----
__global__ void cvt_kernel(const void* __restrict__ src, float* __restrict__ dst,
                           int n, const int* __restrict__ flag) {
    int i = blockIdx.x * 256 + threadIdx.x;
    if (i >= n) return;
    if (*flag) dst[i] = bits2f(((const u16*)src)[i]);
    else       dst[i] = ((const float*)src)[i];
}

// ---------------- LayerNorm: one block (256 thr) per token, D=1024 ----------------
__global__ void ln_kernel(const float* __restrict__ xin, const float* __restrict__ g,
                          const float* __restrict__ b, float* __restrict__ out) {
    int t = blockIdx.x, tid = threadIdx.x;
    float4 f = ((const float4*)(xin + (size_t)t * DM))[tid];
    float v0 = f.x, v1 = f.y, v2 = f.z, v3 = f.w;
    float s  = v0 + v1 + v2 + v3;
    float ss = v0*v0 + v1*v1 + v2*v2 + v3*v3;
    #pragma unroll
    for (int o = 32; o > 0; o >>= 1) {
        s  += __shfl_down(s,  o, 64);
        ss += __shfl_down(ss, o, 64);
    }
    __shared__ float rs[4], rss[4];
    int w = tid >> 6, lane = tid & 63;
    if (!lane) { rs[w] = s; rss[w] = ss; }
    __syncthreads();
    s  = rs[0] + rs[1] + rs[2] + rs[3];
    ss = rss[0] + rss[1] + rss[2] + rss[3];
    float mean = s * (1.0f / DM);
    float var  = ss * (1.0f / DM) - mean * mean;
    float rstd = rsqrtf(var + 1e-5f);
    float4 gu = ((const float4*)g)[tid];
    float4 bu = ((const float4*)b)[tid];
    float4 o;
    o.x = (v0 - mean) * rstd * gu.x + bu.x;
    o.y = (v1 - mean) * rstd * gu.y + bu.y;
    o.z = (v2 - mean) * rstd * gu.z + bu.z;
    o.w = (v3 - mean) * rstd * gu.w + bu.w;
    ((float4*)(out + (size_t)t * DM))[tid] = o;
}

// ------- SGEMM NT: C[M,N] = A[M,K] * W[N,K]^T + bias, opt GELU/resid -------
// 64x64 tile, BK=16, 256 threads, 4x4 per thread. All fp32.
template<int GELU, int RESID>
__global__ void gemm_nt(const float* __restrict__ A, const float* __restrict__ W,
                        const float* __restrict__ bias, const float* __restrict__ resid,
                        float* __restrict__ Cout, int M, int N, int K) {
    __shared__ __align__(16) float As[16][68];
    __shared__ __align__(16) float Ws[16][68];
    int tid = threadIdx.x;
    int m0 = blockIdx.y << 6, n0 = blockIdx.x << 6;
    int tx = tid & 15, ty = tid >> 4;
    int lm = tid >> 2, lk = (tid & 3) << 2;
    float acc[4][4] = {};
    const float* Aptr = A + (size_t)(m0 + lm) * K + lk;
    const float* Wptr = W + (size_t)(n0 + lm) * K + lk;
    for (int kt = 0; kt < K; kt += 16) {
        float4 av = *(const float4*)(Aptr + kt);
        float4 wv = *(const float4*)(Wptr + kt);
        As[lk+0][lm] = av.x; As[lk+1][lm] = av.y; As[lk+2][lm] = av.z; As[lk+3][lm] = av.w;
        Ws[lk+0][lm] = wv.x; Ws[lk+1][lm] = wv.y; Ws[lk+2][lm] = wv.z; Ws[lk+3][lm] = wv.w;
        __syncthreads();
        #pragma unroll
        for (int kk = 0; kk < 16; kk++) {
            float4 af = *(const float4*)&As[kk][ty << 2];
            float4 wf = *(const float4*)&Ws[kk][tx << 2];
            acc[0][0] += af.x*wf.x; acc[0][1] += af.x*wf.y; acc[0][2] += af.x*wf.z; acc[0][3] += af.x*wf.w;
            acc[1][0] += af.y*wf.x; acc[1][1] += af.y*wf.y; acc[1][2] += af.y*wf.z; acc[1][3] += af.y*wf.w;
            acc[2][0] += af.z*wf.x; acc[2][1] += af.z*wf.y; acc[2][2] += af.z*wf.z; acc[2][3] += af.z*wf.w;
            acc[3][0] += af.w*wf.x; acc[3][1] += af.w*wf.y; acc[3][2] += af.w*wf.z; acc[3][3] += af.w*wf.w;
        }
        __syncthreads();
    }
    float bv[4];
    #pragma unroll
    for (int j = 0; j < 4; j++) bv[j] = bias[n0 + (tx << 2) + j];
    #pragma unroll
    for (int i = 0; i < 4; i++) {
        int row = m0 + (ty << 2) + i;
        int col = n0 + (tx << 2);
        float o[4];
        #pragma unroll
        for (int j = 0; j < 4; j++) {
            float val = acc[i][j] + bv[j];
            if (GELU)  val = 0.5f * val * (1.0f + erff(val * 0.70710678118654752f));
            if (RESID) val += resid[(size_t)row * N + col + j];
            o[j] = val;
        }
        *(float4*)(Cout + (size_t)row * N + col) = make_float4(o[0], o[1], o[2], o[3]);
    }
}

// ---------------- Attention: one block per (b, h, 4 q-rows), full softmax ----------------
__global__ void attn_kernel(const float* __restrict__ Q, const float* __restrict__ K,
                            const float* __restrict__ V, float* __restrict__ O) {
    __shared__ __align__(16) float qs[QT][HD];
    __shared__ float sc[QT][SQ];          // 32 KB
    __shared__ float redA[QT][4], redB[QT][4];
    __shared__ float pacc[4][QT][HD];     // 4 KB
    int bid = blockIdx.x;
    int qb  = bid & (SQ / QT - 1);        // 512 q-blocks
    int bh  = bid >> 9;
    int h   = bh & (NHEADS - 1), b = bh >> 4;
    int tid = threadIdx.x;
    int lane = tid & 63, wid = tid >> 6;
    size_t base = ((size_t)b * SQ) * DM + h * HD;
    {   // load 4 q rows (exactly 256 elements)
        int qr = tid >> 6, d = tid & 63;
        qs[qr][d] = Q[base + (size_t)(qb * QT + qr) * DM + d];
    }
    __syncthreads();
    const float scale = 0.125f;  // 64^-0.5
    #pragma unroll
    for (int r = 0; r < SQ / 256; r++) {
        int kidx = (r << 8) + tid;
        const float* kr = K + base + (size_t)kidx * DM;
        float d0 = 0, d1 = 0, d2 = 0, d3 = 0;
        #pragma unroll
        for (int d = 0; d < HD; d += 4) {
            float4 kv = *(const float4*)(kr + d);
            float4 q0 = *(const float4*)&qs[0][d];
            float4 q1 = *(const float4*)&qs[1][d];
            float4 q2 = *(const float4*)&qs[2][d];
            float4 q3 = *(const float4*)&qs[3][d];
            d0 += q0.x*kv.x + q0.y*kv.y + q0.z*kv.z + q0.w*kv.w;
            d1 += q1.x*kv.x + q1.y*kv.y + q1.z*kv.z + q1.w*kv.w;
            d2 += q2.x*kv.x + q2.y*kv.y + q2.z*kv.z + q2.w*kv.w;
            d3 += q3.x*kv.x + q3.y*kv.y + q3.z*kv.z + q3.w*kv.w;
        }
        sc[0][kidx] = d0 * scale; sc[1][kidx] = d1 * scale;
        sc[2][kidx] = d2 * scale; sc[3][kidx] = d3 * scale;
    }
    __syncthreads();
    float mx[QT] = {-1e30f, -1e30f, -1e30f, -1e30f};
    for (int r = 0; r < SQ / 256; r++) {
        int kidx = (r << 8) + tid;
        #pragma unroll
        for (int qr = 0; qr < QT; qr++) mx[qr] = fmaxf(mx[qr], sc[qr][kidx]);
    }
    #pragma unroll
    for (int qr = 0; qr < QT; qr++)
        #pragma unroll
        for (int o = 32; o > 0; o >>= 1) mx[qr] = fmaxf(mx[qr], __shfl_down(mx[qr], o, 64));
    if (!lane) { for (int qr = 0; qr < QT; qr++) redA[qr][wid] = mx[qr]; }
    __syncthreads();
    #pragma unroll
    for (int qr = 0; qr < QT; qr++)
        mx[qr] = fmaxf(fmaxf(redA[qr][0], redA[qr][1]), fmaxf(redA[qr][2], redA[qr][3]));
    float sm[QT] = {0, 0, 0, 0};
    for (int r = 0; r < SQ / 256; r++) {
        int kidx = (r << 8) + tid;
        #pragma unroll
        for (int qr = 0; qr < QT; qr++) {
            float e = __expf(sc[qr][kidx] - mx[qr]);
            sc[qr][kidx] = e;
            sm[qr] += e;
        }
    }
    #pragma unroll
    for (int qr = 0; qr < QT; qr++)
        #pragma unroll
        for (int o = 32; o > 0; o >>= 1) sm[qr] += __shfl_down(sm[qr], o, 64);
    if (!lane) { for (int qr = 0; qr < QT; qr++) redB[qr][wid] = sm[qr]; }
    __syncthreads();
    float inv[QT];
    #pragma unroll
    for (int qr = 0; qr < QT; qr++)
        inv[qr] = 1.0f / (redB[qr][0] + redB[qr][1] + redB[qr][2] + redB[qr][3]);
    int d = tid & 63, g = tid >> 6;
    float a0 = 0, a1 = 0, a2 = 0, a3 = 0;
    const float* vp = V + base + d;
    for (int k2 = g * (SQ / 4); k2 < (g + 1) * (SQ / 4); k2++) {
        float vv = vp[(size_t)k2 * DM];
        a0 += sc[0][k2] * vv; a1 += sc[1][k2] * vv;
        a2 += sc[2][k2] * vv; a3 += sc[3][k2] * vv;
    }
    pacc[g][0][d] = a0; pacc[g][1][d] = a1; pacc[g][2][d] = a2; pacc[g][3][d] = a3;
    __syncthreads();
    {
        int qr = tid >> 6, dd = tid & 63;
        float o = (pacc[0][qr][dd] + pacc[1][qr][dd] + pacc[2][qr][dd] + pacc[3][qr][dd]) * inv[qr];
        O[base + (size_t)(qb * QT + qr) * DM + dd] = o;
    }
}

extern "C" void kernel_launch(void* const* d_in, const int* in_sizes, int n_in,
                              void* d_out, int out_size, void* d_ws, size_t ws_size,
                              hipStream_t stream) {
    if (n_in < 17) return;
    if (in_sizes[0] != (int)NX || in_sizes[11] != (int)NW1 || in_sizes[13] != (int)NW2) return;

    float* F = (float*)d_ws;
    // converted-input region
    size_t off = 0;
    float* xf  = F + off; off += NX;
    float* wqf = F + off; off += NW;
    float* wkf = F + off; off += NW;
    float* wvf = F + off; off += NW;
    float* wof = F + off; off += NW;
    float* w1f = F + off; off += NW1;
    float* w2f = F + off; off += NW2;
    float* bqf = F + off; off += DM;
    float* bkf = F + off; off += DM;
    float* bvf = F + off; off += DM;
    float* bof = F + off; off += DM;
    float* b1f = F + off; off += HM;
    float* b2f = F + off; off += DM;
    float* g1f = F + off; off += DM;
    float* e1f = F + off; off += DM;
    float* g2f = F + off; off += DM;
    float* e2f = F + off; off += DM;
    // compute region
    float* xn1 = F + off; off += NX;   // xn1, later xn2
    float* q   = F + off; off += NX;   // q, later y
    float* k   = F + off; off += NX;
    float* v   = F + off; off += NX;
    float* ao  = F + off; off += NX;
    float* hb  = F + off; off += (size_t)NTOK * HM;
    int*  flag = (int*)(F + off); off += 1;
    if (ws_size < off * sizeof(float)) return;  // diagnostic: absmax == max|ref|

    dim3 blk(256);
    probe_kernel<<<1, blk, 0, stream>>>((const u16*)d_in[0], flag);

    float* dsts[17] = {xf, wqf, bqf, wkf, bkf, wvf, bvf, wof, bof,
                       g1f, e1f, w1f, b1f, w2f, b2f, g2f, e2f};
    for (int i = 0; i < 17; i++) {
        int n = in_sizes[i];
        cvt_kernel<<<(n + 255) / 256, blk, 0, stream>>>(d_in[i], dsts[i], n, flag);
    }

    dim3 gD(DM / 64, NTOK / 64);
    dim3 gH(HM / 64, NTOK / 64);

    // xn1 = LN1(x)
    ln_kernel<<<NTOK, blk, 0, stream>>>(xf, g1f, e1f, xn1);
    // q/k/v = xn1 @ w{q,k,v}^T + b
    gemm_nt<0,0><<<gD, blk, 0, stream>>>(xn1, wqf, bqf, nullptr, q, NTOK, DM, DM);
    gemm_nt<0,0><<<gD, blk, 0, stream>>>(xn1, wkf, bkf, nullptr, k, NTOK, DM, DM);
    gemm_nt<0,0><<<gD, blk, 0, stream>>>(xn1, wvf, bvf, nullptr, v, NTOK, DM, DM);
    // ao = softmax(q k^T / 8) v
    attn_kernel<<<NBATCH * NHEADS * (SQ / QT), blk, 0, stream>>>(q, k, v, ao);
    // y = xn1 + ao @ wo^T + bo   (into q buffer)
    gemm_nt<0,1><<<gD, blk, 0, stream>>>(ao, wof, bof, xn1, q, NTOK, DM, DM);
    // xn2 = LN2(y)               (into xn1 buffer)
    ln_kernel<<<NTOK, blk, 0, stream>>>(q, g2f, e2f, xn1);
    // h = gelu(xn2 @ w1^T + b1)
    gemm_nt<1,0><<<gH, blk, 0, stream>>>(xn1, w1f, b1f, nullptr, hb, NTOK, HM, DM);
    // out = xn2 + h @ w2^T + b2  (fp32 store)
    gemm_nt<0,1><<<gD, blk, 0, stream>>>(hb, w2f, b2f, xn1, (float*)d_out, NTOK, DM, HM);
}

// Round 4
// 2832.651 us; speedup vs baseline: 3.0402x; 3.0402x over previous
//
#include <hip/hip_runtime.h>
#include <hip/hip_bf16.h>

#define DM 1024      // d_model
#define HM 4096      // ffn hidden
#define NHEADS 16
#define HD 64        // head dim
#define SQ 2048      // seq len
#define NBATCH 2
#define NTOK 4096    // NBATCH*SQ

#define NX  ((size_t)NTOK * DM)

// ---------------- LayerNorm: one block (256 thr) per token, D=1024 ----------------
__global__ void ln_kernel(const float* __restrict__ xin, const float* __restrict__ g,
                          const float* __restrict__ b, float* __restrict__ out) {
    int t = blockIdx.x, tid = threadIdx.x;
    float4 f = ((const float4*)(xin + (size_t)t * DM))[tid];
    float v0 = f.x, v1 = f.y, v2 = f.z, v3 = f.w;
    float s  = v0 + v1 + v2 + v3;
    float ss = v0*v0 + v1*v1 + v2*v2 + v3*v3;
    #pragma unroll
    for (int o = 32; o > 0; o >>= 1) {
        s  += __shfl_down(s,  o, 64);
        ss += __shfl_down(ss, o, 64);
    }
    __shared__ float rs[4], rss[4];
    int w = tid >> 6, lane = tid & 63;
    if (!lane) { rs[w] = s; rss[w] = ss; }
    __syncthreads();
    s  = rs[0] + rs[1] + rs[2] + rs[3];
    ss = rss[0] + rss[1] + rss[2] + rss[3];
    float mean = s * (1.0f / DM);
    float var  = ss * (1.0f / DM) - mean * mean;
    float rstd = rsqrtf(var + 1e-5f);
    float4 gu = ((const float4*)g)[tid];
    float4 bu = ((const float4*)b)[tid];
    float4 o;
    o.x = (v0 - mean) * rstd * gu.x + bu.x;
    o.y = (v1 - mean) * rstd * gu.y + bu.y;
    o.z = (v2 - mean) * rstd * gu.z + bu.z;
    o.w = (v3 - mean) * rstd * gu.w + bu.w;
    ((float4*)(out + (size_t)t * DM))[tid] = o;
}

// ------- SGEMM NT: C[M,N] = A[M,K] * W[N,K]^T + bias, opt GELU/resid -------
template<int GELU, int RESID>
__global__ void gemm_nt(const float* __restrict__ A, const float* __restrict__ W,
                        const float* __restrict__ bias, const float* __restrict__ resid,
                        float* __restrict__ Cout, int M, int N, int K) {
    __shared__ __align__(16) float As[16][68];
    __shared__ __align__(16) float Ws[16][68];
    int tid = threadIdx.x;
    int m0 = blockIdx.y << 6, n0 = blockIdx.x << 6;
    int tx = tid & 15, ty = tid >> 4;
    int lm = tid >> 2, lk = (tid & 3) << 2;
    float acc[4][4] = {};
    const float* Aptr = A + (size_t)(m0 + lm) * K + lk;
    const float* Wptr = W + (size_t)(n0 + lm) * K + lk;
    for (int kt = 0; kt < K; kt += 16) {
        float4 av = *(const float4*)(Aptr + kt);
        float4 wv = *(const float4*)(Wptr + kt);
        As[lk+0][lm] = av.x; As[lk+1][lm] = av.y; As[lk+2][lm] = av.z; As[lk+3][lm] = av.w;
        Ws[lk+0][lm] = wv.x; Ws[lk+1][lm] = wv.y; Ws[lk+2][lm] = wv.z; Ws[lk+3][lm] = wv.w;
        __syncthreads();
        #pragma unroll
        for (int kk = 0; kk < 16; kk++) {
            float4 af = *(const float4*)&As[kk][ty << 2];
            float4 wf = *(const float4*)&Ws[kk][tx << 2];
            acc[0][0] += af.x*wf.x; acc[0][1] += af.x*wf.y; acc[0][2] += af.x*wf.z; acc[0][3] += af.x*wf.w;
            acc[1][0] += af.y*wf.x; acc[1][1] += af.y*wf.y; acc[1][2] += af.y*wf.z; acc[1][3] += af.y*wf.w;
            acc[2][0] += af.z*wf.x; acc[2][1] += af.z*wf.y; acc[2][2] += af.z*wf.z; acc[2][3] += af.z*wf.w;
            acc[3][0] += af.w*wf.x; acc[3][1] += af.w*wf.y; acc[3][2] += af.w*wf.z; acc[3][3] += af.w*wf.w;
        }
        __syncthreads();
    }
    float bv[4];
    #pragma unroll
    for (int j = 0; j < 4; j++) bv[j] = bias[n0 + (tx << 2) + j];
    #pragma unroll
    for (int i = 0; i < 4; i++) {
        int row = m0 + (ty << 2) + i;
        int col = n0 + (tx << 2);
        float o[4];
        #pragma unroll
        for (int j = 0; j < 4; j++) {
            float val = acc[i][j] + bv[j];
            if (GELU)  val = 0.5f * val * (1.0f + erff(val * 0.70710678118654752f));
            if (RESID) val += resid[(size_t)row * N + col + j];
            o[j] = val;
        }
        *(float4*)(Cout + (size_t)row * N + col) = make_float4(o[0], o[1], o[2], o[3]);
    }
}

// ---------------- Flash attention: one block per (b, h, 64-row q-tile) ----------------
// 256 threads; online softmax over 32 k-tiles of 64. fp32 VALU.
__global__ __launch_bounds__(256) void fattn_kernel(const float* __restrict__ Q,
                                                    const float* __restrict__ K,
                                                    const float* __restrict__ V,
                                                    float* __restrict__ O) {
    __shared__ __align__(16) float Qs[64][68];
    __shared__ __align__(16) float Ks[64][68];
    __shared__ __align__(16) float Vs[64][68];
    __shared__ __align__(16) float Ps[64][68];
    __shared__ float mrow[64], lrow[64], arow[64];
    __shared__ float red[4][64];
    int bid = blockIdx.x;
    int qt  = bid & 31;          // 32 q-tiles
    int bh  = bid >> 5;
    int h   = bh & (NHEADS - 1), b = bh >> 4;
    int tid = threadIdx.x;
    int tx  = tid & 15, ty = tid >> 4;
    size_t base = ((size_t)b * SQ) * DM + h * HD;

    {   // load Q tile (64 rows x 64 cols)
        int rr = tid >> 4, cc = (tid & 15) << 2;
        #pragma unroll
        for (int p = 0; p < 4; p++) {
            int r = (p << 4) + rr;
            *(float4*)&Qs[r][cc] = *(const float4*)(Q + base + (size_t)(qt * 64 + r) * DM + cc);
        }
    }
    if (tid < 64) { mrow[tid] = -1e30f; lrow[tid] = 0.0f; }
    float acc[4][4] = {};
    __syncthreads();

    for (int kt = 0; kt < SQ / 64; kt++) {
        {   // load K,V tiles
            int rr = tid >> 4, cc = (tid & 15) << 2;
            #pragma unroll
            for (int p = 0; p < 4; p++) {
                int r = (p << 4) + rr;
                *(float4*)&Ks[r][cc] = *(const float4*)(K + base + (size_t)(kt * 64 + r) * DM + cc);
                *(float4*)&Vs[r][cc] = *(const float4*)(V + base + (size_t)(kt * 64 + r) * DM + cc);
            }
        }
        __syncthreads();
        // S = scale * Q K^T, 4x4 per thread
        float s[4][4] = {};
        #pragma unroll
        for (int d = 0; d < HD; d += 4) {
            float4 qf[4], kf[4];
            #pragma unroll
            for (int i = 0; i < 4; i++) qf[i] = *(const float4*)&Qs[(ty << 2) + i][d];
            #pragma unroll
            for (int j = 0; j < 4; j++) kf[j] = *(const float4*)&Ks[(tx << 2) + j][d];
            #pragma unroll
            for (int i = 0; i < 4; i++)
                #pragma unroll
                for (int j = 0; j < 4; j++)
                    s[i][j] += qf[i].x*kf[j].x + qf[i].y*kf[j].y + qf[i].z*kf[j].z + qf[i].w*kf[j].w;
        }
        #pragma unroll
        for (int i = 0; i < 4; i++)
            #pragma unroll
            for (int j = 0; j < 4; j++)
                Ps[(ty << 2) + i][(tx << 2) + j] = s[i][j] * 0.125f;
        __syncthreads();
        {   // row-max partials
            int r = tid & 63, part = tid >> 6, k0 = part << 4;
            float m = -1e30f;
            #pragma unroll
            for (int kk = 0; kk < 16; kk++) m = fmaxf(m, Ps[r][k0 + kk]);
            red[part][r] = m;
        }
        __syncthreads();
        if (tid < 64) {
            int r = tid;
            float mt = fmaxf(fmaxf(red[0][r], red[1][r]), fmaxf(red[2][r], red[3][r]));
            float mo = mrow[r];
            float mn = fmaxf(mo, mt);
            mrow[r] = mn;
            arow[r] = __expf(mo - mn);   // first tile: exp(-1e30 - finite) -> 0
        }
        __syncthreads();
        {   // P = exp(S - m), row-sum partials
            int r = tid & 63, part = tid >> 6, k0 = part << 4;
            float mn = mrow[r];
            float sum = 0.0f;
            #pragma unroll
            for (int kk = 0; kk < 16; kk++) {
                float e = __expf(Ps[r][k0 + kk] - mn);
                Ps[r][k0 + kk] = e;
                sum += e;
            }
            red[part][r] = sum;
        }
        __syncthreads();
        if (tid < 64) {
            int r = tid;
            lrow[r] = arow[r] * lrow[r] + red[0][r] + red[1][r] + red[2][r] + red[3][r];
        }
        // O = alpha*O + P V
        float al[4];
        #pragma unroll
        for (int i = 0; i < 4; i++) al[i] = arow[(ty << 2) + i];
        #pragma unroll
        for (int i = 0; i < 4; i++)
            #pragma unroll
            for (int j = 0; j < 4; j++) acc[i][j] *= al[i];
        #pragma unroll
        for (int k4 = 0; k4 < 64; k4 += 4) {
            float4 pf[4], vf[4];
            #pragma unroll
            for (int i = 0; i < 4; i++) pf[i] = *(const float4*)&Ps[(ty << 2) + i][k4];
            #pragma unroll
            for (int kk = 0; kk < 4; kk++) vf[kk] = *(const float4*)&Vs[k4 + kk][tx << 2];
            #pragma unroll
            for (int i = 0; i < 4; i++) {
                acc[i][0] += pf[i].x*vf[0].x + pf[i].y*vf[1].x + pf[i].z*vf[2].x + pf[i].w*vf[3].x;
                acc[i][1] += pf[i].x*vf[0].y + pf[i].y*vf[1].y + pf[i].z*vf[2].y + pf[i].w*vf[3].y;
                acc[i][2] += pf[i].x*vf[0].z + pf[i].y*vf[1].z + pf[i].z*vf[2].z + pf[i].w*vf[3].z;
                acc[i][3] += pf[i].x*vf[0].w + pf[i].y*vf[1].w + pf[i].z*vf[2].w + pf[i].w*vf[3].w;
            }
        }
        __syncthreads();
    }
    // O[r][d] = acc / l
    #pragma unroll
    for (int i = 0; i < 4; i++) {
        int r = (ty << 2) + i;
        float inv = 1.0f / lrow[r];
        float4 o = make_float4(acc[i][0]*inv, acc[i][1]*inv, acc[i][2]*inv, acc[i][3]*inv);
        *(float4*)(O + base + (size_t)(qt * 64 + r) * DM + (tx << 2)) = o;
    }
}

extern "C" void kernel_launch(void* const* d_in, const int* in_sizes, int n_in,
                              void* d_out, int out_size, void* d_ws, size_t ws_size,
                              hipStream_t stream) {
    if (n_in < 17) return;
    const float* x   = (const float*)d_in[0];
    const float* wq  = (const float*)d_in[1];
    const float* bq  = (const float*)d_in[2];
    const float* wk  = (const float*)d_in[3];
    const float* bk  = (const float*)d_in[4];
    const float* wv  = (const float*)d_in[5];
    const float* bv  = (const float*)d_in[6];
    const float* wo  = (const float*)d_in[7];
    const float* bo  = (const float*)d_in[8];
    const float* g1  = (const float*)d_in[9];
    const float* e1  = (const float*)d_in[10];
    const float* w1  = (const float*)d_in[11];
    const float* b1  = (const float*)d_in[12];
    const float* w2  = (const float*)d_in[13];
    const float* b2  = (const float*)d_in[14];
    const float* g2  = (const float*)d_in[15];
    const float* e2  = (const float*)d_in[16];

    // workspace layout (fp32): xn1 | q | k | v | ao | h   -> ~144 MB
    size_t need = ((size_t)5 * NX + (size_t)NTOK * HM) * sizeof(float);
    if (ws_size < need) return;
    float* ws  = (float*)d_ws;
    float* xn1 = ws;                   // xn1, later xn2
    float* q   = ws + NX;              // q, later y
    float* k   = ws + 2 * NX;
    float* v   = ws + 3 * NX;
    float* ao  = ws + 4 * NX;
    float* hb  = ws + 5 * NX;          // 4096x4096

    dim3 blk(256);
    dim3 gD(DM / 64, NTOK / 64);
    dim3 gH(HM / 64, NTOK / 64);

    // xn1 = LN1(x)
    ln_kernel<<<NTOK, blk, 0, stream>>>(x, g1, e1, xn1);
    // q/k/v = xn1 @ w{q,k,v}^T + b
    gemm_nt<0,0><<<gD, blk, 0, stream>>>(xn1, wq, bq, nullptr, q, NTOK, DM, DM);
    gemm_nt<0,0><<<gD, blk, 0, stream>>>(xn1, wk, bk, nullptr, k, NTOK, DM, DM);
    gemm_nt<0,0><<<gD, blk, 0, stream>>>(xn1, wv, bv, nullptr, v, NTOK, DM, DM);
    // ao = softmax(q k^T / 8) v   (flash, 1024 blocks)
    fattn_kernel<<<NBATCH * NHEADS * (SQ / 64), blk, 0, stream>>>(q, k, v, ao);
    // y = xn1 + ao @ wo^T + bo   (into q buffer)
    gemm_nt<0,1><<<gD, blk, 0, stream>>>(ao, wo, bo, xn1, q, NTOK, DM, DM);
    // xn2 = LN2(y)               (into xn1 buffer)
    ln_kernel<<<NTOK, blk, 0, stream>>>(q, g2, e2, xn1);
    // h = gelu(xn2 @ w1^T + b1)
    gemm_nt<1,0><<<gH, blk, 0, stream>>>(xn1, w1, b1, nullptr, hb, NTOK, HM, DM);
    // out = xn2 + h @ w2^T + b2  (fp32 store)
    gemm_nt<0,1><<<gD, blk, 0, stream>>>(hb, w2, b2, xn1, (float*)d_out, NTOK, DM, HM);
}

// Round 5
// 1495.907 us; speedup vs baseline: 5.7570x; 1.8936x over previous
//
#include <hip/hip_runtime.h>
#include <hip/hip_bf16.h>

typedef unsigned short u16;
typedef __attribute__((ext_vector_type(8))) short short8;   // 8 bf16 (4 VGPRs)
typedef __attribute__((ext_vector_type(4))) float f32x4;    // 4 fp32 acc

#define DM 1024      // d_model
#define HM 4096      // ffn hidden
#define NHEADS 16
#define HD 64        // head dim
#define SQ 2048      // seq len
#define NBATCH 2
#define NTOK 4096    // NBATCH*SQ

#define NX  ((size_t)NTOK * DM)

__device__ __forceinline__ u16 f2b(float f) {   // fp32 -> bf16 RNE
    union { float f; unsigned int i; } w; w.f = f;
    unsigned int x = w.i;
    return (u16)((x + 0x7FFFu + ((x >> 16) & 1u)) >> 16);
}

__device__ __forceinline__ void gload_lds16(const void* g, void* l) {
    __builtin_amdgcn_global_load_lds(
        (const __attribute__((address_space(1))) void*)g,
        (__attribute__((address_space(3))) void*)l, 16, 0, 0);
}

// ---- fp32 -> bf16 conversion (4 elems/thread) ----
__global__ void cvt_bf(const float* __restrict__ src, u16* __restrict__ dst, int n4) {
    int i = blockIdx.x * 256 + threadIdx.x;
    if (i >= n4) return;
    float4 f = ((const float4*)src)[i];
    ushort4 o; o.x = f2b(f.x); o.y = f2b(f.y); o.z = f2b(f.z); o.w = f2b(f.w);
    ((ushort4*)dst)[i] = o;
}

// ---- pack qkv biases into one fp32 vector [3072] ----
__global__ void pack_bias(const float* __restrict__ bq, const float* __restrict__ bk,
                          const float* __restrict__ bv, float* __restrict__ dst) {
    int i = blockIdx.x * 256 + threadIdx.x;
    if (i >= 3 * DM) return;
    float v = (i < DM) ? bq[i] : (i < 2 * DM) ? bk[i - DM] : bv[i - 2 * DM];
    dst[i] = v;
}

// ---------------- LayerNorm: fp32 in, fp32 + bf16 out ----------------
__global__ void ln_kernel(const float* __restrict__ xin, const float* __restrict__ g,
                          const float* __restrict__ b, float* __restrict__ outf,
                          u16* __restrict__ outb) {
    int t = blockIdx.x, tid = threadIdx.x;
    float4 f = ((const float4*)(xin + (size_t)t * DM))[tid];
    float v0 = f.x, v1 = f.y, v2 = f.z, v3 = f.w;
    float s  = v0 + v1 + v2 + v3;
    float ss = v0*v0 + v1*v1 + v2*v2 + v3*v3;
    #pragma unroll
    for (int o = 32; o > 0; o >>= 1) {
        s  += __shfl_down(s,  o, 64);
        ss += __shfl_down(ss, o, 64);
    }
    __shared__ float rs[4], rss[4];
    int w = tid >> 6, lane = tid & 63;
    if (!lane) { rs[w] = s; rss[w] = ss; }
    __syncthreads();
    s  = rs[0] + rs[1] + rs[2] + rs[3];
    ss = rss[0] + rss[1] + rss[2] + rss[3];
    float mean = s * (1.0f / DM);
    float var  = ss * (1.0f / DM) - mean * mean;
    float rstd = rsqrtf(var + 1e-5f);
    float4 gu = ((const float4*)g)[tid];
    float4 bu = ((const float4*)b)[tid];
    float4 o;
    o.x = (v0 - mean) * rstd * gu.x + bu.x;
    o.y = (v1 - mean) * rstd * gu.y + bu.y;
    o.z = (v2 - mean) * rstd * gu.z + bu.z;
    o.w = (v3 - mean) * rstd * gu.w + bu.w;
    ((float4*)(outf + (size_t)t * DM))[tid] = o;
    ushort4 ob; ob.x = f2b(o.x); ob.y = f2b(o.y); ob.z = f2b(o.z); ob.w = f2b(o.w);
    ((ushort4*)(outb + (size_t)t * DM))[tid] = ob;
}

// ------- MFMA GEMM (m97 structure): C[M,N] = A[M,K]·W[N,K]^T + bias -------
// A,W bf16 row-major. 128x128 tile, BK=32, 256 thr / 4 waves, each wave 64x64.
// global_load_lds width=16 staging; ds_read_b128 fragments; 16x16x32 bf16 MFMA.
template<int GELU, int RESID, int OUTBF>
__global__ __launch_bounds__(256, 2)
void gemm_bt(const u16* __restrict__ A, const u16* __restrict__ W,
             const float* __restrict__ bias, const float* __restrict__ resid,
             void* __restrict__ Cout, int M, int N, int K) {
    __shared__ __attribute__((aligned(16))) u16 As[128 * 32];   // 8 KB
    __shared__ __attribute__((aligned(16))) u16 Bs[128 * 32];   // 8 KB
    int tid  = threadIdx.x;
    int wid  = tid >> 6, lane = tid & 63;
    int m0 = blockIdx.y << 7, n0 = blockIdx.x << 7;
    int wm = (wid & 1) << 6, wn = (wid >> 1) << 6;

    // staging: wave stages segments {2w,2w+1} of A and of B (16 rows each,
    // 1024 B per segment; lane l -> row seg*16 + l/4, bf16 cols (l&3)*8..+7)
    int seg0 = wid << 1;
    int rIn  = lane >> 2;
    int cIn  = (lane & 3) << 3;
    const u16* aG0 = A + (size_t)(m0 + (seg0 << 4) + rIn) * K + cIn;
    const u16* aG1 = A + (size_t)(m0 + ((seg0 + 1) << 4) + rIn) * K + cIn;
    const u16* bG0 = W + (size_t)(n0 + (seg0 << 4) + rIn) * K + cIn;
    const u16* bG1 = W + (size_t)(n0 + ((seg0 + 1) << 4) + rIn) * K + cIn;
    u16* aL0 = As + (seg0 << 9);        // seg*512 u16 = seg*1024 B
    u16* aL1 = As + ((seg0 + 1) << 9);
    u16* bL0 = Bs + (seg0 << 9);
    u16* bL1 = Bs + ((seg0 + 1) << 9);

    int fr = lane & 15;            // frag row (m or n)
    int fc = (lane >> 4) << 3;     // frag k-offset (0,8,16,24)

    f32x4 acc[4][4];
    #pragma unroll
    for (int i = 0; i < 4; i++)
        #pragma unroll
        for (int j = 0; j < 4; j++)
            acc[i][j] = (f32x4){0.f, 0.f, 0.f, 0.f};

    for (int k0 = 0; k0 < K; k0 += 32) {
        gload_lds16(aG0 + k0, aL0);
        gload_lds16(aG1 + k0, aL1);
        gload_lds16(bG0 + k0, bL0);
        gload_lds16(bG1 + k0, bL1);
        __syncthreads();
        short8 af[4], bf[4];
        #pragma unroll
        for (int mi = 0; mi < 4; mi++)
            af[mi] = *(const short8*)(As + (size_t)(wm + (mi << 4) + fr) * 32 + fc);
        #pragma unroll
        for (int ni = 0; ni < 4; ni++)
            bf[ni] = *(const short8*)(Bs + (size_t)(wn + (ni << 4) + fr) * 32 + fc);
        #pragma unroll
        for (int mi = 0; mi < 4; mi++)
            #pragma unroll
            for (int ni = 0; ni < 4; ni++)
                acc[mi][ni] = __builtin_amdgcn_mfma_f32_16x16x32_bf16(
                    af[mi], bf[ni], acc[mi][ni], 0, 0, 0);
        __syncthreads();
    }

    // epilogue: C/D layout col=lane&15, row=(lane>>4)*4+reg
    int erow = (lane >> 4) << 2;
    #pragma unroll
    for (int ni = 0; ni < 4; ni++) {
        int col = n0 + wn + (ni << 4) + fr;
        float bv = bias[col];
        #pragma unroll
        for (int mi = 0; mi < 4; mi++) {
            #pragma unroll
            for (int r = 0; r < 4; r++) {
                int row = m0 + wm + (mi << 4) + erow + r;
                float val = acc[mi][ni][r] + bv;
                if (GELU)  val = 0.5f * val * (1.0f + erff(val * 0.70710678118654752f));
                if (RESID) val += resid[(size_t)row * N + col];
                if (OUTBF) ((u16*)Cout)[(size_t)row * N + col] = f2b(val);
                else       ((float*)Cout)[(size_t)row * N + col] = val;
            }
        }
    }
}

// ---------------- Flash attention: fp32 VALU, strided QKV input, bf16 out ----------------
__global__ __launch_bounds__(256) void fattn_kernel(const float* __restrict__ Q,
                                                    const float* __restrict__ K,
                                                    const float* __restrict__ V,
                                                    u16* __restrict__ O, int ld) {
    __shared__ __align__(16) float Qs[64][68];
    __shared__ __align__(16) float Ks[64][68];
    __shared__ __align__(16) float Vs[64][68];
    __shared__ __align__(16) float Ps[64][68];
    __shared__ float mrow[64], lrow[64], arow[64];
    __shared__ float red[4][64];
    int bid = blockIdx.x;
    int qt  = bid & 31;
    int bh  = bid >> 5;
    int h   = bh & (NHEADS - 1), b = bh >> 4;
    int tid = threadIdx.x;
    int tx  = tid & 15, ty = tid >> 4;
    size_t base  = ((size_t)b * SQ) * ld + h * HD;
    size_t obase = ((size_t)b * SQ) * DM + h * HD;

    {
        int rr = tid >> 4, cc = (tid & 15) << 2;
        #pragma unroll
        for (int p = 0; p < 4; p++) {
            int r = (p << 4) + rr;
            *(float4*)&Qs[r][cc] = *(const float4*)(Q + base + (size_t)(qt * 64 + r) * ld + cc);
        }
    }
    if (tid < 64) { mrow[tid] = -1e30f; lrow[tid] = 0.0f; }
    float acc[4][4] = {};
    __syncthreads();

    for (int kt = 0; kt < SQ / 64; kt++) {
        {
            int rr = tid >> 4, cc = (tid & 15) << 2;
            #pragma unroll
            for (int p = 0; p < 4; p++) {
                int r = (p << 4) + rr;
                *(float4*)&Ks[r][cc] = *(const float4*)(K + base + (size_t)(kt * 64 + r) * ld + cc);
                *(float4*)&Vs[r][cc] = *(const float4*)(V + base + (size_t)(kt * 64 + r) * ld + cc);
            }
        }
        __syncthreads();
        float s[4][4] = {};
        #pragma unroll
        for (int d = 0; d < HD; d += 4) {
            float4 qf[4], kf[4];
            #pragma unroll
            for (int i = 0; i < 4; i++) qf[i] = *(const float4*)&Qs[(ty << 2) + i][d];
            #pragma unroll
            for (int j = 0; j < 4; j++) kf[j] = *(const float4*)&Ks[(tx << 2) + j][d];
            #pragma unroll
            for (int i = 0; i < 4; i++)
                #pragma unroll
                for (int j = 0; j < 4; j++)
                    s[i][j] += qf[i].x*kf[j].x + qf[i].y*kf[j].y + qf[i].z*kf[j].z + qf[i].w*kf[j].w;
        }
        #pragma unroll
        for (int i = 0; i < 4; i++)
            #pragma unroll
            for (int j = 0; j < 4; j++)
                Ps[(ty << 2) + i][(tx << 2) + j] = s[i][j] * 0.125f;
        __syncthreads();
        {
            int r = tid & 63, part = tid >> 6, k0 = part << 4;
            float m = -1e30f;
            #pragma unroll
            for (int kk = 0; kk < 16; kk++) m = fmaxf(m, Ps[r][k0 + kk]);
            red[part][r] = m;
        }
        __syncthreads();
        if (tid < 64) {
            int r = tid;
            float mt = fmaxf(fmaxf(red[0][r], red[1][r]), fmaxf(red[2][r], red[3][r]));
            float mo = mrow[r];
            float mn = fmaxf(mo, mt);
            mrow[r] = mn;
            arow[r] = __expf(mo - mn);
        }
        __syncthreads();
        {
            int r = tid & 63, part = tid >> 6, k0 = part << 4;
            float mn = mrow[r];
            float sum = 0.0f;
            #pragma unroll
            for (int kk = 0; kk < 16; kk++) {
                float e = __expf(Ps[r][k0 + kk] - mn);
                Ps[r][k0 + kk] = e;
                sum += e;
            }
            red[part][r] = sum;
        }
        __syncthreads();
        if (tid < 64) {
            int r = tid;
            lrow[r] = arow[r] * lrow[r] + red[0][r] + red[1][r] + red[2][r] + red[3][r];
        }
        float al[4];
        #pragma unroll
        for (int i = 0; i < 4; i++) al[i] = arow[(ty << 2) + i];
        #pragma unroll
        for (int i = 0; i < 4; i++)
            #pragma unroll
            for (int j = 0; j < 4; j++) acc[i][j] *= al[i];
        #pragma unroll
        for (int k4 = 0; k4 < 64; k4 += 4) {
            float4 pf[4], vf[4];
            #pragma unroll
            for (int i = 0; i < 4; i++) pf[i] = *(const float4*)&Ps[(ty << 2) + i][k4];
            #pragma unroll
            for (int kk = 0; kk < 4; kk++) vf[kk] = *(const float4*)&Vs[k4 + kk][tx << 2];
            #pragma unroll
            for (int i = 0; i < 4; i++) {
                acc[i][0] += pf[i].x*vf[0].x + pf[i].y*vf[1].x + pf[i].z*vf[2].x + pf[i].w*vf[3].x;
                acc[i][1] += pf[i].x*vf[0].y + pf[i].y*vf[1].y + pf[i].z*vf[2].y + pf[i].w*vf[3].y;
                acc[i][2] += pf[i].x*vf[0].z + pf[i].y*vf[1].z + pf[i].z*vf[2].z + pf[i].w*vf[3].z;
                acc[i][3] += pf[i].x*vf[0].w + pf[i].y*vf[1].w + pf[i].z*vf[2].w + pf[i].w*vf[3].w;
            }
        }
        __syncthreads();
    }
    #pragma unroll
    for (int i = 0; i < 4; i++) {
        int r = (ty << 2) + i;
        float inv = 1.0f / lrow[r];
        ushort4 o;
        o.x = f2b(acc[i][0] * inv); o.y = f2b(acc[i][1] * inv);
        o.z = f2b(acc[i][2] * inv); o.w = f2b(acc[i][3] * inv);
        *(ushort4*)(O + obase + (size_t)(qt * 64 + r) * DM + (tx << 2)) = o;
    }
}

extern "C" void kernel_launch(void* const* d_in, const int* in_sizes, int n_in,
                              void* d_out, int out_size, void* d_ws, size_t ws_size,
                              hipStream_t stream) {
    if (n_in < 17) return;
    const float* x   = (const float*)d_in[0];
    const float* wq  = (const float*)d_in[1];
    const float* bq  = (const float*)d_in[2];
    const float* wk  = (const float*)d_in[3];
    const float* bk  = (const float*)d_in[4];
    const float* wv  = (const float*)d_in[5];
    const float* bv  = (const float*)d_in[6];
    const float* wo  = (const float*)d_in[7];
    const float* bo  = (const float*)d_in[8];
    const float* g1  = (const float*)d_in[9];
    const float* e1  = (const float*)d_in[10];
    const float* w1  = (const float*)d_in[11];
    const float* b1  = (const float*)d_in[12];
    const float* w2  = (const float*)d_in[13];
    const float* b2  = (const float*)d_in[14];
    const float* g2  = (const float*)d_in[15];
    const float* e2  = (const float*)d_in[16];

    // workspace layout (fp32 units):
    float* F = (float*)d_ws;
    size_t off = 0;
    float* xnf   = F + off; off += NX;                 // LN out fp32 (xn1 then xn2)
    u16*   xnb   = (u16*)(F + off); off += NX / 2;     // LN out bf16
    float* qkv   = F + off; off += (size_t)NTOK * 3 * DM;  // fused QKV fp32; later y aliases
    u16*   aob   = (u16*)(F + off); off += NX / 2;     // attention out bf16
    u16*   hb    = (u16*)(F + off); off += (size_t)NTOK * HM / 2;  // FFN hidden bf16
    u16*   wqkvb = (u16*)(F + off); off += (size_t)3 * DM * DM / 2;
    u16*   wob   = (u16*)(F + off); off += (size_t)DM * DM / 2;
    u16*   w1b   = (u16*)(F + off); off += (size_t)HM * DM / 2;
    u16*   w2b   = (u16*)(F + off); off += (size_t)DM * HM / 2;
    float* bqkv  = F + off; off += 3 * DM;
    if (ws_size < off * sizeof(float)) return;
    float* y = qkv;   // alias: qkv dead after attention

    dim3 blk(256);
    // weights -> bf16 (wq/wk/wv packed into wqkvb rows 0..3071)
    cvt_bf<<<(DM * DM / 4 + 255) / 256, blk, 0, stream>>>(wq, wqkvb, DM * DM / 4);
    cvt_bf<<<(DM * DM / 4 + 255) / 256, blk, 0, stream>>>(wk, wqkvb + (size_t)DM * DM, DM * DM / 4);
    cvt_bf<<<(DM * DM / 4 + 255) / 256, blk, 0, stream>>>(wv, wqkvb + (size_t)2 * DM * DM, DM * DM / 4);
    cvt_bf<<<(DM * DM / 4 + 255) / 256, blk, 0, stream>>>(wo, wob, DM * DM / 4);
    cvt_bf<<<(HM * DM / 4 + 255) / 256, blk, 0, stream>>>(w1, w1b, HM * DM / 4);
    cvt_bf<<<(DM * HM / 4 + 255) / 256, blk, 0, stream>>>(w2, w2b, DM * HM / 4);
    pack_bias<<<(3 * DM + 255) / 256, blk, 0, stream>>>(bq, bk, bv, bqkv);

    // xn1 = LN1(x)
    ln_kernel<<<NTOK, blk, 0, stream>>>(x, g1, e1, xnf, xnb);
    // qkv = xn1 @ [wq|wk|wv]^T + b   (M=4096, N=3072, K=1024)
    gemm_bt<0,0,0><<<dim3(3 * DM / 128, NTOK / 128), blk, 0, stream>>>(
        xnb, wqkvb, bqkv, nullptr, qkv, NTOK, 3 * DM, DM);
    // aob = softmax(q k^T / 8) v   (flash fp32, strided input, bf16 out)
    fattn_kernel<<<NBATCH * NHEADS * (SQ / 64), blk, 0, stream>>>(
        qkv, qkv + DM, qkv + 2 * DM, aob, 3 * DM);
    // y = xn1 + aob @ wo^T + bo
    gemm_bt<0,1,0><<<dim3(DM / 128, NTOK / 128), blk, 0, stream>>>(
        aob, wob, bo, xnf, y, NTOK, DM, DM);
    // xn2 = LN2(y)
    ln_kernel<<<NTOK, blk, 0, stream>>>(y, g2, e2, xnf, xnb);
    // hb = gelu(xn2 @ w1^T + b1)   (bf16 out)
    gemm_bt<1,0,1><<<dim3(HM / 128, NTOK / 128), blk, 0, stream>>>(
        xnb, w1b, b1, nullptr, hb, NTOK, HM, DM);
    // out = xn2 + hb @ w2^T + b2   (fp32 out)
    gemm_bt<0,1,0><<<dim3(DM / 128, NTOK / 128), blk, 0, stream>>>(
        hb, w2b, b2, xnf, d_out, NTOK, DM, HM);
}

// Round 6
// 494.124 us; speedup vs baseline: 17.4286x; 3.0274x over previous
//
#include <hip/hip_runtime.h>
#include <hip/hip_bf16.h>

typedef unsigned short u16;
typedef __attribute__((ext_vector_type(8))) short short8;   // 8 bf16 (4 VGPRs)
typedef __attribute__((ext_vector_type(4))) float f32x4;    // 4 fp32 acc

#define DM 1024      // d_model
#define HM 4096      // ffn hidden
#define NHEADS 16
#define HD 64        // head dim
#define SQ 2048      // seq len
#define NBATCH 2
#define NTOK 4096    // NBATCH*SQ

#define NX  ((size_t)NTOK * DM)

__device__ __forceinline__ u16 f2b(float f) {   // fp32 -> bf16 RNE
    union { float f; unsigned int i; } w; w.f = f;
    unsigned int x = w.i;
    return (u16)((x + 0x7FFFu + ((x >> 16) & 1u)) >> 16);
}

__device__ __forceinline__ void gload_lds16(const void* g, void* l) {
    __builtin_amdgcn_global_load_lds(
        (const __attribute__((address_space(1))) void*)g,
        (__attribute__((address_space(3))) void*)l, 16, 0, 0);
}

// ---- fp32 -> bf16 conversion (4 elems/thread) ----
__global__ void cvt_bf(const float* __restrict__ src, u16* __restrict__ dst, int n4) {
    int i = blockIdx.x * 256 + threadIdx.x;
    if (i >= n4) return;
    float4 f = ((const float4*)src)[i];
    ushort4 o; o.x = f2b(f.x); o.y = f2b(f.y); o.z = f2b(f.z); o.w = f2b(f.w);
    ((ushort4*)dst)[i] = o;
}

// ---- pack qkv biases into one fp32 vector [3072] ----
__global__ void pack_bias(const float* __restrict__ bq, const float* __restrict__ bk,
                          const float* __restrict__ bv, float* __restrict__ dst) {
    int i = blockIdx.x * 256 + threadIdx.x;
    if (i >= 3 * DM) return;
    float v = (i < DM) ? bq[i] : (i < 2 * DM) ? bk[i - DM] : bv[i - 2 * DM];
    dst[i] = v;
}

// ---------------- LayerNorm: fp32 in, fp32 + bf16 out ----------------
__global__ void ln_kernel(const float* __restrict__ xin, const float* __restrict__ g,
                          const float* __restrict__ b, float* __restrict__ outf,
                          u16* __restrict__ outb) {
    int t = blockIdx.x, tid = threadIdx.x;
    float4 f = ((const float4*)(xin + (size_t)t * DM))[tid];
    float v0 = f.x, v1 = f.y, v2 = f.z, v3 = f.w;
    float s  = v0 + v1 + v2 + v3;
    float ss = v0*v0 + v1*v1 + v2*v2 + v3*v3;
    #pragma unroll
    for (int o = 32; o > 0; o >>= 1) {
        s  += __shfl_down(s,  o, 64);
        ss += __shfl_down(ss, o, 64);
    }
    __shared__ float rs[4], rss[4];
    int w = tid >> 6, lane = tid & 63;
    if (!lane) { rs[w] = s; rss[w] = ss; }
    __syncthreads();
    s  = rs[0] + rs[1] + rs[2] + rs[3];
    ss = rss[0] + rss[1] + rss[2] + rss[3];
    float mean = s * (1.0f / DM);
    float var  = ss * (1.0f / DM) - mean * mean;
    float rstd = rsqrtf(var + 1e-5f);
    float4 gu = ((const float4*)g)[tid];
    float4 bu = ((const float4*)b)[tid];
    float4 o;
    o.x = (v0 - mean) * rstd * gu.x + bu.x;
    o.y = (v1 - mean) * rstd * gu.y + bu.y;
    o.z = (v2 - mean) * rstd * gu.z + bu.z;
    o.w = (v3 - mean) * rstd * gu.w + bu.w;
    ((float4*)(outf + (size_t)t * DM))[tid] = o;
    ushort4 ob; ob.x = f2b(o.x); ob.y = f2b(o.y); ob.z = f2b(o.z); ob.w = f2b(o.w);
    ((ushort4*)(outb + (size_t)t * DM))[tid] = ob;
}

// ------- MFMA GEMM (m97 structure): C[M,N] = A[M,K]·W[N,K]^T + bias -------
template<int GELU, int RESID, int OUTBF>
__global__ __launch_bounds__(256, 2)
void gemm_bt(const u16* __restrict__ A, const u16* __restrict__ W,
             const float* __restrict__ bias, const float* __restrict__ resid,
             void* __restrict__ Cout, int M, int N, int K) {
    __shared__ __attribute__((aligned(16))) u16 As[128 * 32];
    __shared__ __attribute__((aligned(16))) u16 Bs[128 * 32];
    int tid  = threadIdx.x;
    int wid  = tid >> 6, lane = tid & 63;
    int m0 = blockIdx.y << 7, n0 = blockIdx.x << 7;
    int wm = (wid & 1) << 6, wn = (wid >> 1) << 6;

    int seg0 = wid << 1;
    int rIn  = lane >> 2;
    int cIn  = (lane & 3) << 3;
    const u16* aG0 = A + (size_t)(m0 + (seg0 << 4) + rIn) * K + cIn;
    const u16* aG1 = A + (size_t)(m0 + ((seg0 + 1) << 4) + rIn) * K + cIn;
    const u16* bG0 = W + (size_t)(n0 + (seg0 << 4) + rIn) * K + cIn;
    const u16* bG1 = W + (size_t)(n0 + ((seg0 + 1) << 4) + rIn) * K + cIn;
    u16* aL0 = As + (seg0 << 9);
    u16* aL1 = As + ((seg0 + 1) << 9);
    u16* bL0 = Bs + (seg0 << 9);
    u16* bL1 = Bs + ((seg0 + 1) << 9);

    int fr = lane & 15;
    int fc = (lane >> 4) << 3;

    f32x4 acc[4][4];
    #pragma unroll
    for (int i = 0; i < 4; i++)
        #pragma unroll
        for (int j = 0; j < 4; j++)
            acc[i][j] = (f32x4){0.f, 0.f, 0.f, 0.f};

    for (int k0 = 0; k0 < K; k0 += 32) {
        gload_lds16(aG0 + k0, aL0);
        gload_lds16(aG1 + k0, aL1);
        gload_lds16(bG0 + k0, bL0);
        gload_lds16(bG1 + k0, bL1);
        __syncthreads();
        short8 af[4], bf[4];
        #pragma unroll
        for (int mi = 0; mi < 4; mi++)
            af[mi] = *(const short8*)(As + (size_t)(wm + (mi << 4) + fr) * 32 + fc);
        #pragma unroll
        for (int ni = 0; ni < 4; ni++)
            bf[ni] = *(const short8*)(Bs + (size_t)(wn + (ni << 4) + fr) * 32 + fc);
        #pragma unroll
        for (int mi = 0; mi < 4; mi++)
            #pragma unroll
            for (int ni = 0; ni < 4; ni++)
                acc[mi][ni] = __builtin_amdgcn_mfma_f32_16x16x32_bf16(
                    af[mi], bf[ni], acc[mi][ni], 0, 0, 0);
        __syncthreads();
    }

    int erow = (lane >> 4) << 2;
    #pragma unroll
    for (int ni = 0; ni < 4; ni++) {
        int col = n0 + wn + (ni << 4) + fr;
        float bv = bias[col];
        #pragma unroll
        for (int mi = 0; mi < 4; mi++) {
            #pragma unroll
            for (int r = 0; r < 4; r++) {
                int row = m0 + wm + (mi << 4) + erow + r;
                float val = acc[mi][ni][r] + bv;
                if (GELU)  val = 0.5f * val * (1.0f + erff(val * 0.70710678118654752f));
                if (RESID) val += resid[(size_t)row * N + col];
                if (OUTBF) ((u16*)Cout)[(size_t)row * N + col] = f2b(val);
                else       ((float*)Cout)[(size_t)row * N + col] = val;
            }
        }
    }
}

// ---------------- MFMA flash attention ----------------
// 1024 blocks x 256 thr. Q-tile 64 rows; wave w owns rows 16w..16w+15.
// K staged via global_load_lds into chunked [2][64][32] bf16; V staged transposed.
// Online softmax in C/D-layout registers via shfl_xor over the 16 col-lanes.
__global__ __launch_bounds__(256) void fattn_mfma(const u16* __restrict__ QKV,
                                                  u16* __restrict__ O) {
    __shared__ __attribute__((aligned(16))) u16 Qs[4096];      // [2][64][32]
    __shared__ __attribute__((aligned(16))) u16 Ks[4096];
    __shared__ __attribute__((aligned(16))) u16 Vt[4096];      // [2][64 d][32 k]
    __shared__ __attribute__((aligned(16))) u16 Ps[4][1024];   // per-wave [2][16][32]
    const int ld = 3 * DM;
    int bid = blockIdx.x;
    int qt = bid & 31, bh = bid >> 5;
    int h = bh & (NHEADS - 1), b = bh >> 4;
    int tid = threadIdx.x, wid = tid >> 6, lane = tid & 63;
    int fr = lane & 15, fc = (lane >> 4) << 3;
    size_t tokb = (size_t)b * SQ;
    const u16* Qg = QKV + tokb * ld + h * HD;
    const u16* Kg = QKV + tokb * ld + DM + h * HD;
    const u16* Vg = QKV + tokb * ld + 2 * DM + h * HD;

    {   // stage Q tile: segments s = 2w, 2w+1; seg s covers chunk s>>2, rows (s&3)*16..+15
        int s0 = wid << 1;
        #pragma unroll
        for (int t = 0; t < 2; t++) {
            int s = s0 + t;
            const u16* g = Qg + (size_t)(qt * 64 + ((s & 3) << 4) + (lane >> 2)) * ld
                         + ((s >> 2) << 5) + ((lane & 3) << 3);
            gload_lds16(g, Qs + (s << 9));
        }
    }
    float m_old[4] = {-1e30f, -1e30f, -1e30f, -1e30f};
    float l_old[4] = {0.f, 0.f, 0.f, 0.f};
    f32x4 oacc[4];
    #pragma unroll
    for (int di = 0; di < 4; di++) oacc[di] = (f32x4){0.f, 0.f, 0.f, 0.f};
    int vk = tid & 63, vd0 = (tid >> 6) << 4;
    __syncthreads();

    for (int kt = 0; kt < SQ / 64; kt++) {
        {   // stage K tile
            int s0 = wid << 1;
            #pragma unroll
            for (int t = 0; t < 2; t++) {
                int s = s0 + t;
                const u16* g = Kg + (size_t)(kt * 64 + ((s & 3) << 4) + (lane >> 2)) * ld
                             + ((s >> 2) << 5) + ((lane & 3) << 3);
                gload_lds16(g, Ks + (s << 9));
            }
        }
        {   // stage V transposed: thread -> key vk, dims vd0..vd0+15
            const u16* vrow = Vg + (size_t)(kt * 64 + vk) * ld + vd0;
            int cbase = (vk >> 5) << 11;    // chunk * 2048
            int kk = vk & 31;
            #pragma unroll
            for (int j = 0; j < 4; j++) {
                ushort4 vv = *(const ushort4*)(vrow + (j << 2));
                int d = vd0 + (j << 2);
                Vt[cbase + (d + 0) * 32 + kk] = vv.x;
                Vt[cbase + (d + 1) * 32 + kk] = vv.y;
                Vt[cbase + (d + 2) * 32 + kk] = vv.z;
                Vt[cbase + (d + 3) * 32 + kk] = vv.w;
            }
        }
        __syncthreads();
        // S = scale * Q K^T   (wave slab: rows 16w..16w+15 x 64 cols)
        short8 aq0 = *(const short8*)(Qs + ((wid << 4) + fr) * 32 + fc);
        short8 aq1 = *(const short8*)(Qs + 2048 + ((wid << 4) + fr) * 32 + fc);
        f32x4 s[4];
        #pragma unroll
        for (int ni = 0; ni < 4; ni++) {
            short8 bk0 = *(const short8*)(Ks + ((ni << 4) + fr) * 32 + fc);
            short8 bk1 = *(const short8*)(Ks + 2048 + ((ni << 4) + fr) * 32 + fc);
            f32x4 z = (f32x4){0.f, 0.f, 0.f, 0.f};
            z = __builtin_amdgcn_mfma_f32_16x16x32_bf16(aq0, bk0, z, 0, 0, 0);
            z = __builtin_amdgcn_mfma_f32_16x16x32_bf16(aq1, bk1, z, 0, 0, 0);
            #pragma unroll
            for (int r = 0; r < 4; r++) z[r] *= 0.125f;
            s[ni] = z;
        }
        // online softmax in registers (rows r: q = 16w + (lane>>4)*4 + r)
        float mt[4], alpha[4];
        #pragma unroll
        for (int r = 0; r < 4; r++)
            mt[r] = fmaxf(fmaxf(s[0][r], s[1][r]), fmaxf(s[2][r], s[3][r]));
        #pragma unroll
        for (int msk = 1; msk <= 8; msk <<= 1)
            #pragma unroll
            for (int r = 0; r < 4; r++) mt[r] = fmaxf(mt[r], __shfl_xor(mt[r], msk, 64));
        #pragma unroll
        for (int r = 0; r < 4; r++) {
            float mn = fmaxf(m_old[r], mt[r]);
            alpha[r] = __expf(m_old[r] - mn);
            m_old[r] = mn;
        }
        float ps[4] = {0.f, 0.f, 0.f, 0.f};
        #pragma unroll
        for (int ni = 0; ni < 4; ni++)
            #pragma unroll
            for (int r = 0; r < 4; r++) {
                float e = __expf(s[ni][r] - m_old[r]);
                s[ni][r] = e;
                ps[r] += e;
            }
        #pragma unroll
        for (int msk = 1; msk <= 8; msk <<= 1)
            #pragma unroll
            for (int r = 0; r < 4; r++) ps[r] += __shfl_xor(ps[r], msk, 64);
        #pragma unroll
        for (int r = 0; r < 4; r++) l_old[r] = alpha[r] * l_old[r] + ps[r];
        #pragma unroll
        for (int di = 0; di < 4; di++)
            #pragma unroll
            for (int r = 0; r < 4; r++) oacc[di][r] *= alpha[r];
        // write P slab to wave-private LDS in A-frag chunked layout [2][16][32]
        #pragma unroll
        for (int ni = 0; ni < 4; ni++) {
            int c  = (ni << 4) + fr;
            int cb = (c >> 5) << 9;
            int kk = c & 31;
            #pragma unroll
            for (int r = 0; r < 4; r++)
                Ps[wid][cb + (((lane >> 4) << 2) + r) * 32 + kk] = f2b(s[ni][r]);
        }
        __syncthreads();
        // O += P V
        short8 ap0 = *(const short8*)(&Ps[wid][fr * 32 + fc]);
        short8 ap1 = *(const short8*)(&Ps[wid][512 + fr * 32 + fc]);
        #pragma unroll
        for (int di = 0; di < 4; di++) {
            short8 bv0 = *(const short8*)(Vt + ((di << 4) + fr) * 32 + fc);
            short8 bv1 = *(const short8*)(Vt + 2048 + ((di << 4) + fr) * 32 + fc);
            oacc[di] = __builtin_amdgcn_mfma_f32_16x16x32_bf16(ap0, bv0, oacc[di], 0, 0, 0);
            oacc[di] = __builtin_amdgcn_mfma_f32_16x16x32_bf16(ap1, bv1, oacc[di], 0, 0, 0);
        }
        __syncthreads();
    }
    float inv[4];
    #pragma unroll
    for (int r = 0; r < 4; r++) inv[r] = 1.0f / l_old[r];
    #pragma unroll
    for (int di = 0; di < 4; di++) {
        int d = (di << 4) + fr;
        #pragma unroll
        for (int r = 0; r < 4; r++) {
            int q = qt * 64 + (wid << 4) + ((lane >> 4) << 2) + r;
            O[(tokb + q) * DM + h * HD + d] = f2b(oacc[di][r] * inv[r]);
        }
    }
}

extern "C" void kernel_launch(void* const* d_in, const int* in_sizes, int n_in,
                              void* d_out, int out_size, void* d_ws, size_t ws_size,
                              hipStream_t stream) {
    if (n_in < 17) return;
    const float* x   = (const float*)d_in[0];
    const float* wq  = (const float*)d_in[1];
    const float* bq  = (const float*)d_in[2];
    const float* wk  = (const float*)d_in[3];
    const float* bk  = (const float*)d_in[4];
    const float* wv  = (const float*)d_in[5];
    const float* bv  = (const float*)d_in[6];
    const float* wo  = (const float*)d_in[7];
    const float* bo  = (const float*)d_in[8];
    const float* g1  = (const float*)d_in[9];
    const float* e1  = (const float*)d_in[10];
    const float* w1  = (const float*)d_in[11];
    const float* b1  = (const float*)d_in[12];
    const float* w2  = (const float*)d_in[13];
    const float* b2  = (const float*)d_in[14];
    const float* g2  = (const float*)d_in[15];
    const float* e2  = (const float*)d_in[16];

    float* F = (float*)d_ws;
    size_t off = 0;
    float* xnf   = F + off; off += NX;
    u16*   xnb   = (u16*)(F + off); off += NX / 2;
    u16*   qkvb  = (u16*)(F + off); off += (size_t)NTOK * 3 * DM / 2;  // bf16 QKV
    float* y     = F + off; off += NX;
    u16*   aob   = (u16*)(F + off); off += NX / 2;
    u16*   hb    = (u16*)(F + off); off += (size_t)NTOK * HM / 2;
    u16*   wqkvb = (u16*)(F + off); off += (size_t)3 * DM * DM / 2;
    u16*   wob   = (u16*)(F + off); off += (size_t)DM * DM / 2;
    u16*   w1b   = (u16*)(F + off); off += (size_t)HM * DM / 2;
    u16*   w2b   = (u16*)(F + off); off += (size_t)DM * HM / 2;
    float* bqkv  = F + off; off += 3 * DM;
    if (ws_size < off * sizeof(float)) return;

    dim3 blk(256);
    cvt_bf<<<(DM * DM / 4 + 255) / 256, blk, 0, stream>>>(wq, wqkvb, DM * DM / 4);
    cvt_bf<<<(DM * DM / 4 + 255) / 256, blk, 0, stream>>>(wk, wqkvb + (size_t)DM * DM, DM * DM / 4);
    cvt_bf<<<(DM * DM / 4 + 255) / 256, blk, 0, stream>>>(wv, wqkvb + (size_t)2 * DM * DM, DM * DM / 4);
    cvt_bf<<<(DM * DM / 4 + 255) / 256, blk, 0, stream>>>(wo, wob, DM * DM / 4);
    cvt_bf<<<(HM * DM / 4 + 255) / 256, blk, 0, stream>>>(w1, w1b, HM * DM / 4);
    cvt_bf<<<(DM * HM / 4 + 255) / 256, blk, 0, stream>>>(w2, w2b, DM * HM / 4);
    pack_bias<<<(3 * DM + 255) / 256, blk, 0, stream>>>(bq, bk, bv, bqkv);

    // xn1 = LN1(x)
    ln_kernel<<<NTOK, blk, 0, stream>>>(x, g1, e1, xnf, xnb);
    // qkv = xn1 @ [wq|wk|wv]^T + b   (bf16 out)
    gemm_bt<0,0,1><<<dim3(3 * DM / 128, NTOK / 128), blk, 0, stream>>>(
        xnb, wqkvb, bqkv, nullptr, qkvb, NTOK, 3 * DM, DM);
    // aob = softmax(q k^T / 8) v   (MFMA flash, bf16)
    fattn_mfma<<<NBATCH * NHEADS * (SQ / 64), blk, 0, stream>>>(qkvb, aob);
    // y = xn1 + aob @ wo^T + bo
    gemm_bt<0,1,0><<<dim3(DM / 128, NTOK / 128), blk, 0, stream>>>(
        aob, wob, bo, xnf, y, NTOK, DM, DM);
    // xn2 = LN2(y)
    ln_kernel<<<NTOK, blk, 0, stream>>>(y, g2, e2, xnf, xnb);
    // hb = gelu(xn2 @ w1^T + b1)   (bf16 out)
    gemm_bt<1,0,1><<<dim3(HM / 128, NTOK / 128), blk, 0, stream>>>(
        xnb, w1b, b1, nullptr, hb, NTOK, HM, DM);
    // out = xn2 + hb @ w2^T + b2   (fp32 out)
    gemm_bt<0,1,0><<<dim3(DM / 128, NTOK / 128), blk, 0, stream>>>(
        hb, w2b, b2, xnf, d_out, NTOK, DM, HM);
}

// Round 7
// 432.146 us; speedup vs baseline: 19.9282x; 1.1434x over previous
//
#include <hip/hip_runtime.h>
#include <hip/hip_bf16.h>

typedef unsigned short u16;
typedef __attribute__((ext_vector_type(8))) short short8;   // 8 bf16 (4 VGPRs)
typedef __attribute__((ext_vector_type(4))) float f32x4;    // 4 fp32 acc

#define DM 1024      // d_model
#define HM 4096      // ffn hidden
#define NHEADS 16
#define HD 64        // head dim
#define SQ 2048      // seq len
#define NBATCH 2
#define NTOK 4096    // NBATCH*SQ

#define NX  ((size_t)NTOK * DM)

__device__ __forceinline__ u16 f2b(float f) {   // fp32 -> bf16 RNE
    union { float f; unsigned int i; } w; w.f = f;
    unsigned int x = w.i;
    return (u16)((x + 0x7FFFu + ((x >> 16) & 1u)) >> 16);
}
__device__ __forceinline__ u16 f2b_ru(float f) {  // round-half-up (positives)
    union { float f; unsigned int i; } w; w.f = f;
    return (u16)((w.i + 0x8000u) >> 16);
}

__device__ __forceinline__ void gload_lds16(const void* g, void* l) {
    __builtin_amdgcn_global_load_lds(
        (const __attribute__((address_space(1))) void*)g,
        (__attribute__((address_space(3))) void*)l, 16, 0, 0);
}

// ---- fp32 -> bf16 conversion with scale ----
__global__ void cvt_bf(const float* __restrict__ src, u16* __restrict__ dst,
                       int n4, float scale) {
    int i = blockIdx.x * 256 + threadIdx.x;
    if (i >= n4) return;
    float4 f = ((const float4*)src)[i];
    ushort4 o;
    o.x = f2b(f.x * scale); o.y = f2b(f.y * scale);
    o.z = f2b(f.z * scale); o.w = f2b(f.w * scale);
    ((ushort4*)dst)[i] = o;
}

// ---- pack qkv biases (bq scaled by 0.125 to match scaled wq) ----
__global__ void pack_bias(const float* __restrict__ bq, const float* __restrict__ bk,
                          const float* __restrict__ bv, float* __restrict__ dst) {
    int i = blockIdx.x * 256 + threadIdx.x;
    if (i >= 3 * DM) return;
    float v = (i < DM) ? bq[i] * 0.125f : (i < 2 * DM) ? bk[i - DM] : bv[i - 2 * DM];
    dst[i] = v;
}

// ---------------- LayerNorm: fp32 in, fp32 + bf16 out ----------------
__global__ void ln_kernel(const float* __restrict__ xin, const float* __restrict__ g,
                          const float* __restrict__ b, float* __restrict__ outf,
                          u16* __restrict__ outb) {
    int t = blockIdx.x, tid = threadIdx.x;
    float4 f = ((const float4*)(xin + (size_t)t * DM))[tid];
    float v0 = f.x, v1 = f.y, v2 = f.z, v3 = f.w;
    float s  = v0 + v1 + v2 + v3;
    float ss = v0*v0 + v1*v1 + v2*v2 + v3*v3;
    #pragma unroll
    for (int o = 32; o > 0; o >>= 1) {
        s  += __shfl_down(s,  o, 64);
        ss += __shfl_down(ss, o, 64);
    }
    __shared__ float rs[4], rss[4];
    int w = tid >> 6, lane = tid & 63;
    if (!lane) { rs[w] = s; rss[w] = ss; }
    __syncthreads();
    s  = rs[0] + rs[1] + rs[2] + rs[3];
    ss = rss[0] + rss[1] + rss[2] + rss[3];
    float mean = s * (1.0f / DM);
    float var  = ss * (1.0f / DM) - mean * mean;
    float rstd = rsqrtf(var + 1e-5f);
    float4 gu = ((const float4*)g)[tid];
    float4 bu = ((const float4*)b)[tid];
    float4 o;
    o.x = (v0 - mean) * rstd * gu.x + bu.x;
    o.y = (v1 - mean) * rstd * gu.y + bu.y;
    o.z = (v2 - mean) * rstd * gu.z + bu.z;
    o.w = (v3 - mean) * rstd * gu.w + bu.w;
    ((float4*)(outf + (size_t)t * DM))[tid] = o;
    ushort4 ob; ob.x = f2b(o.x); ob.y = f2b(o.y); ob.z = f2b(o.z); ob.w = f2b(o.w);
    ((ushort4*)(outb + (size_t)t * DM))[tid] = ob;
}

// ------- MFMA GEMM 128x128 (m97 structure): C = A·W^T + bias -------
template<int GELU, int RESID, int OUTBF>
__global__ __launch_bounds__(256, 2)
void gemm_bt(const u16* __restrict__ A, const u16* __restrict__ W,
             const float* __restrict__ bias, const float* __restrict__ resid,
             void* __restrict__ Cout, int M, int N, int K) {
    __shared__ __attribute__((aligned(16))) u16 As[128 * 32];
    __shared__ __attribute__((aligned(16))) u16 Bs[128 * 32];
    int tid  = threadIdx.x;
    int wid  = tid >> 6, lane = tid & 63;
    int m0 = blockIdx.y << 7, n0 = blockIdx.x << 7;
    int wm = (wid & 1) << 6, wn = (wid >> 1) << 6;

    int seg0 = wid << 1;
    int rIn  = lane >> 2;
    int cIn  = (lane & 3) << 3;
    const u16* aG0 = A + (size_t)(m0 + (seg0 << 4) + rIn) * K + cIn;
    const u16* aG1 = A + (size_t)(m0 + ((seg0 + 1) << 4) + rIn) * K + cIn;
    const u16* bG0 = W + (size_t)(n0 + (seg0 << 4) + rIn) * K + cIn;
    const u16* bG1 = W + (size_t)(n0 + ((seg0 + 1) << 4) + rIn) * K + cIn;
    u16* aL0 = As + (seg0 << 9);
    u16* aL1 = As + ((seg0 + 1) << 9);
    u16* bL0 = Bs + (seg0 << 9);
    u16* bL1 = Bs + ((seg0 + 1) << 9);

    int fr = lane & 15;
    int fc = (lane >> 4) << 3;

    f32x4 acc[4][4];
    #pragma unroll
    for (int i = 0; i < 4; i++)
        #pragma unroll
        for (int j = 0; j < 4; j++)
            acc[i][j] = (f32x4){0.f, 0.f, 0.f, 0.f};

    for (int k0 = 0; k0 < K; k0 += 32) {
        gload_lds16(aG0 + k0, aL0);
        gload_lds16(aG1 + k0, aL1);
        gload_lds16(bG0 + k0, bL0);
        gload_lds16(bG1 + k0, bL1);
        __syncthreads();
        short8 af[4], bf[4];
        #pragma unroll
        for (int mi = 0; mi < 4; mi++)
            af[mi] = *(const short8*)(As + (size_t)(wm + (mi << 4) + fr) * 32 + fc);
        #pragma unroll
        for (int ni = 0; ni < 4; ni++)
            bf[ni] = *(const short8*)(Bs + (size_t)(wn + (ni << 4) + fr) * 32 + fc);
        #pragma unroll
        for (int mi = 0; mi < 4; mi++)
            #pragma unroll
            for (int ni = 0; ni < 4; ni++)
                acc[mi][ni] = __builtin_amdgcn_mfma_f32_16x16x32_bf16(
                    af[mi], bf[ni], acc[mi][ni], 0, 0, 0);
        __syncthreads();
    }

    int erow = (lane >> 4) << 2;
    #pragma unroll
    for (int ni = 0; ni < 4; ni++) {
        int col = n0 + wn + (ni << 4) + fr;
        float bv = bias[col];
        #pragma unroll
        for (int mi = 0; mi < 4; mi++) {
            #pragma unroll
            for (int r = 0; r < 4; r++) {
                int row = m0 + wm + (mi << 4) + erow + r;
                float val = acc[mi][ni][r] + bv;
                if (GELU)  val = 0.5f * val * (1.0f + erff(val * 0.70710678118654752f));
                if (RESID) val += resid[(size_t)row * N + col];
                if (OUTBF) ((u16*)Cout)[(size_t)row * N + col] = f2b(val);
                else       ((float*)Cout)[(size_t)row * N + col] = val;
            }
        }
    }
}

// ------- MFMA GEMM 128x64 tile (for N=1024 outputs: more blocks, 2/CU) -------
template<int GELU, int RESID, int OUTBF>
__global__ __launch_bounds__(256, 2)
void gemm_n64(const u16* __restrict__ A, const u16* __restrict__ W,
              const float* __restrict__ bias, const float* __restrict__ resid,
              void* __restrict__ Cout, int M, int N, int K) {
    __shared__ __attribute__((aligned(16))) u16 As[128 * 32];
    __shared__ __attribute__((aligned(16))) u16 Bs[64 * 32];
    int tid  = threadIdx.x;
    int wid  = tid >> 6, lane = tid & 63;
    int m0 = blockIdx.y << 7, n0 = blockIdx.x << 6;
    int wm = (wid & 1) << 6, wn = (wid >> 1) << 5;   // wave: 64 rows x 32 cols

    int seg0 = wid << 1;
    int rIn  = lane >> 2;
    int cIn  = (lane & 3) << 3;
    const u16* aG0 = A + (size_t)(m0 + (seg0 << 4) + rIn) * K + cIn;
    const u16* aG1 = A + (size_t)(m0 + ((seg0 + 1) << 4) + rIn) * K + cIn;
    const u16* bG0 = W + (size_t)(n0 + (wid << 4) + rIn) * K + cIn;   // 1 B-seg/wave
    u16* aL0 = As + (seg0 << 9);
    u16* aL1 = As + ((seg0 + 1) << 9);
    u16* bL0 = Bs + (wid << 9);

    int fr = lane & 15;
    int fc = (lane >> 4) << 3;

    f32x4 acc[4][2];
    #pragma unroll
    for (int i = 0; i < 4; i++)
        #pragma unroll
        for (int j = 0; j < 2; j++)
            acc[i][j] = (f32x4){0.f, 0.f, 0.f, 0.f};

    for (int k0 = 0; k0 < K; k0 += 32) {
        gload_lds16(aG0 + k0, aL0);
        gload_lds16(aG1 + k0, aL1);
        gload_lds16(bG0 + k0, bL0);
        __syncthreads();
        short8 af[4], bf[2];
        #pragma unroll
        for (int mi = 0; mi < 4; mi++)
            af[mi] = *(const short8*)(As + (size_t)(wm + (mi << 4) + fr) * 32 + fc);
        #pragma unroll
        for (int ni = 0; ni < 2; ni++)
            bf[ni] = *(const short8*)(Bs + (size_t)(wn + (ni << 4) + fr) * 32 + fc);
        #pragma unroll
        for (int mi = 0; mi < 4; mi++)
            #pragma unroll
            for (int ni = 0; ni < 2; ni++)
                acc[mi][ni] = __builtin_amdgcn_mfma_f32_16x16x32_bf16(
                    af[mi], bf[ni], acc[mi][ni], 0, 0, 0);
        __syncthreads();
    }

    int erow = (lane >> 4) << 2;
    #pragma unroll
    for (int ni = 0; ni < 2; ni++) {
        int col = n0 + wn + (ni << 4) + fr;
        float bv = bias[col];
        #pragma unroll
        for (int mi = 0; mi < 4; mi++) {
            #pragma unroll
            for (int r = 0; r < 4; r++) {
                int row = m0 + wm + (mi << 4) + erow + r;
                float val = acc[mi][ni][r] + bv;
                if (GELU)  val = 0.5f * val * (1.0f + erff(val * 0.70710678118654752f));
                if (RESID) val += resid[(size_t)row * N + col];
                if (OUTBF) ((u16*)Cout)[(size_t)row * N + col] = f2b(val);
                else       ((float*)Cout)[(size_t)row * N + col] = val;
            }
        }
    }
}

// ---------------- MFMA flash attention v2 ----------------
// No-max softmax (scores bounded; softmax shift-invariant), 0.125 folded into wq.
// Double-buffered K/Vt staging, ONE barrier per k-tile. l reduced once at end.
__global__ __launch_bounds__(256) void fattn_mfma(const u16* __restrict__ QKV,
                                                  u16* __restrict__ O) {
    __shared__ __attribute__((aligned(16))) u16 Qs[4096];        // [2][64][32]
    __shared__ __attribute__((aligned(16))) u16 Ks[2][4096];     // dbuf
    __shared__ __attribute__((aligned(16))) u16 Vt[2][4096];     // dbuf [2][64d][32k]
    __shared__ __attribute__((aligned(16))) u16 Ps[4][1024];     // per-wave [2][16][32]
    const int ld = 3 * DM;
    int bid = blockIdx.x;
    int qt = bid & 31, bh = bid >> 5;
    int h = bh & (NHEADS - 1), b = bh >> 4;
    int tid = threadIdx.x, wid = tid >> 6, lane = tid & 63;
    int fr = lane & 15, fc = (lane >> 4) << 3;
    size_t tokb = (size_t)b * SQ;
    const u16* Qg = QKV + tokb * ld + h * HD;
    const u16* Kg = QKV + tokb * ld + DM + h * HD;
    const u16* Vg = QKV + tokb * ld + 2 * DM + h * HD;
    int vk = lane, vd0 = wid << 4;
    int s0 = wid << 1;

    {   // stage Q tile (seg s: chunk s>>2, rows (s&3)*16; lds off s*512 u16)
        #pragma unroll
        for (int t = 0; t < 2; t++) {
            int s = s0 + t;
            const u16* g = Qg + (size_t)(qt * 64 + ((s & 3) << 4) + (lane >> 2)) * ld
                         + ((s >> 2) << 5) + ((lane & 3) << 3);
            gload_lds16(g, Qs + (s << 9));
        }
    }
    {   // stage K/V tile 0 into buf 0
        #pragma unroll
        for (int t = 0; t < 2; t++) {
            int s = s0 + t;
            const u16* g = Kg + (size_t)(((s & 3) << 4) + (lane >> 2)) * ld
                         + ((s >> 2) << 5) + ((lane & 3) << 3);
            gload_lds16(g, Ks[0] + (s << 9));
        }
        const u16* vrow = Vg + (size_t)vk * ld + vd0;
        int cbase = (vk >> 5) << 11;
        int kk = vk & 31;
        #pragma unroll
        for (int j = 0; j < 4; j++) {
            ushort4 vv = *(const ushort4*)(vrow + (j << 2));
            int d = vd0 + (j << 2);
            Vt[0][cbase + (d + 0) * 32 + kk] = vv.x;
            Vt[0][cbase + (d + 1) * 32 + kk] = vv.y;
            Vt[0][cbase + (d + 2) * 32 + kk] = vv.z;
            Vt[0][cbase + (d + 3) * 32 + kk] = vv.w;
        }
    }
    f32x4 oacc[4];
    #pragma unroll
    for (int di = 0; di < 4; di++) oacc[di] = (f32x4){0.f, 0.f, 0.f, 0.f};
    float lsum[4] = {0.f, 0.f, 0.f, 0.f};
    __syncthreads();   // Q + tile0 visible
    short8 aq0 = *(const short8*)(Qs + ((wid << 4) + fr) * 32 + fc);
    short8 aq1 = *(const short8*)(Qs + 2048 + ((wid << 4) + fr) * 32 + fc);

    for (int kt = 0; kt < SQ / 64; kt++) {
        int buf = kt & 1;
        if (kt + 1 < SQ / 64) {   // prefetch next tile into buf^1
            #pragma unroll
            for (int t = 0; t < 2; t++) {
                int s = s0 + t;
                const u16* g = Kg + (size_t)((kt + 1) * 64 + ((s & 3) << 4) + (lane >> 2)) * ld
                             + ((s >> 2) << 5) + ((lane & 3) << 3);
                gload_lds16(g, Ks[buf ^ 1] + (s << 9));
            }
            const u16* vrow = Vg + (size_t)((kt + 1) * 64 + vk) * ld + vd0;
            int cbase = (vk >> 5) << 11;
            int kk = vk & 31;
            #pragma unroll
            for (int j = 0; j < 4; j++) {
                ushort4 vv = *(const ushort4*)(vrow + (j << 2));
                int d = vd0 + (j << 2);
                Vt[buf ^ 1][cbase + (d + 0) * 32 + kk] = vv.x;
                Vt[buf ^ 1][cbase + (d + 1) * 32 + kk] = vv.y;
                Vt[buf ^ 1][cbase + (d + 2) * 32 + kk] = vv.z;
                Vt[buf ^ 1][cbase + (d + 3) * 32 + kk] = vv.w;
            }
        }
        // S = Q K^T (0.125 pre-folded into wq/bq)
        #pragma unroll
        for (int ni = 0; ni < 4; ni++) {
            short8 bk0 = *(const short8*)(Ks[buf] + ((ni << 4) + fr) * 32 + fc);
            short8 bk1 = *(const short8*)(Ks[buf] + 2048 + ((ni << 4) + fr) * 32 + fc);
            f32x4 z = (f32x4){0.f, 0.f, 0.f, 0.f};
            z = __builtin_amdgcn_mfma_f32_16x16x32_bf16(aq0, bk0, z, 0, 0, 0);
            z = __builtin_amdgcn_mfma_f32_16x16x32_bf16(aq1, bk1, z, 0, 0, 0);
            // P = exp(S); accumulate l; store to wave-private Ps in A-frag layout
            int c  = (ni << 4) + fr;
            int cb = (c >> 5) << 9;
            int kk = c & 31;
            #pragma unroll
            for (int r = 0; r < 4; r++) {
                float e = __expf(z[r]);
                lsum[r] += e;
                Ps[wid][cb + (((lane >> 4) << 2) + r) * 32 + kk] = f2b_ru(e);
            }
        }
        // O += P V
        short8 ap0 = *(const short8*)(&Ps[wid][fr * 32 + fc]);
        short8 ap1 = *(const short8*)(&Ps[wid][512 + fr * 32 + fc]);
        #pragma unroll
        for (int di = 0; di < 4; di++) {
            short8 bv0 = *(const short8*)(Vt[buf] + ((di << 4) + fr) * 32 + fc);
            short8 bv1 = *(const short8*)(Vt[buf] + 2048 + ((di << 4) + fr) * 32 + fc);
            oacc[di] = __builtin_amdgcn_mfma_f32_16x16x32_bf16(ap0, bv0, oacc[di], 0, 0, 0);
            oacc[di] = __builtin_amdgcn_mfma_f32_16x16x32_bf16(ap1, bv1, oacc[di], 0, 0, 0);
        }
        __syncthreads();   // drain prefetch; separate buf reads from next overwrite
    }
    // reduce l across the 16 col-lanes (once)
    #pragma unroll
    for (int msk = 1; msk <= 8; msk <<= 1)
        #pragma unroll
        for (int r = 0; r < 4; r++) lsum[r] += __shfl_xor(lsum[r], msk, 64);
    float inv[4];
    #pragma unroll
    for (int r = 0; r < 4; r++) inv[r] = 1.0f / lsum[r];
    #pragma unroll
    for (int di = 0; di < 4; di++) {
        int d = (di << 4) + fr;
        #pragma unroll
        for (int r = 0; r < 4; r++) {
            int q = qt * 64 + (wid << 4) + ((lane >> 4) << 2) + r;
            O[(tokb + q) * DM + h * HD + d] = f2b(oacc[di][r] * inv[r]);
        }
    }
}

extern "C" void kernel_launch(void* const* d_in, const int* in_sizes, int n_in,
                              void* d_out, int out_size, void* d_ws, size_t ws_size,
                              hipStream_t stream) {
    if (n_in < 17) return;
    const float* x   = (const float*)d_in[0];
    const float* wq  = (const float*)d_in[1];
    const float* bq  = (const float*)d_in[2];
    const float* wk  = (const float*)d_in[3];
    const float* bk  = (const float*)d_in[4];
    const float* wv  = (const float*)d_in[5];
    const float* bv  = (const float*)d_in[6];
    const float* wo  = (const float*)d_in[7];
    const float* bo  = (const float*)d_in[8];
    const float* g1  = (const float*)d_in[9];
    const float* e1  = (const float*)d_in[10];
    const float* w1  = (const float*)d_in[11];
    const float* b1  = (const float*)d_in[12];
    const float* w2  = (const float*)d_in[13];
    const float* b2  = (const float*)d_in[14];
    const float* g2  = (const float*)d_in[15];
    const float* e2  = (const float*)d_in[16];

    float* F = (float*)d_ws;
    size_t off = 0;
    float* xnf   = F + off; off += NX;
    u16*   xnb   = (u16*)(F + off); off += NX / 2;
    u16*   qkvb  = (u16*)(F + off); off += (size_t)NTOK * 3 * DM / 2;
    float* y     = F + off; off += NX;
    u16*   aob   = (u16*)(F + off); off += NX / 2;
    u16*   hb    = (u16*)(F + off); off += (size_t)NTOK * HM / 2;
    u16*   wqkvb = (u16*)(F + off); off += (size_t)3 * DM * DM / 2;
    u16*   wob   = (u16*)(F + off); off += (size_t)DM * DM / 2;
    u16*   w1b   = (u16*)(F + off); off += (size_t)HM * DM / 2;
    u16*   w2b   = (u16*)(F + off); off += (size_t)DM * HM / 2;
    float* bqkv  = F + off; off += 3 * DM;
    if (ws_size < off * sizeof(float)) return;

    dim3 blk(256);
    // wq scaled by 0.125 (attention scale folded into Q projection)
    cvt_bf<<<(DM * DM / 4 + 255) / 256, blk, 0, stream>>>(wq, wqkvb, DM * DM / 4, 0.125f);
    cvt_bf<<<(DM * DM / 4 + 255) / 256, blk, 0, stream>>>(wk, wqkvb + (size_t)DM * DM, DM * DM / 4, 1.0f);
    cvt_bf<<<(DM * DM / 4 + 255) / 256, blk, 0, stream>>>(wv, wqkvb + (size_t)2 * DM * DM, DM * DM / 4, 1.0f);
    cvt_bf<<<(DM * DM / 4 + 255) / 256, blk, 0, stream>>>(wo, wob, DM * DM / 4, 1.0f);
    cvt_bf<<<(HM * DM / 4 + 255) / 256, blk, 0, stream>>>(w1, w1b, HM * DM / 4, 1.0f);
    cvt_bf<<<(DM * HM / 4 + 255) / 256, blk, 0, stream>>>(w2, w2b, DM * HM / 4, 1.0f);
    pack_bias<<<(3 * DM + 255) / 256, blk, 0, stream>>>(bq, bk, bv, bqkv);

    // xn1 = LN1(x)
    ln_kernel<<<NTOK, blk, 0, stream>>>(x, g1, e1, xnf, xnb);
    // qkv = xn1 @ [0.125wq|wk|wv]^T + b   (bf16 out)
    gemm_bt<0,0,1><<<dim3(3 * DM / 128, NTOK / 128), blk, 0, stream>>>(
        xnb, wqkvb, bqkv, nullptr, qkvb, NTOK, 3 * DM, DM);
    // aob = softmax(q k^T) v   (MFMA flash, bf16)
    fattn_mfma<<<NBATCH * NHEADS * (SQ / 64), blk, 0, stream>>>(qkvb, aob);
    // y = xn1 + aob @ wo^T + bo   (128x64 tiles: 512 blocks)
    gemm_n64<0,1,0><<<dim3(DM / 64, NTOK / 128), blk, 0, stream>>>(
        aob, wob, bo, xnf, y, NTOK, DM, DM);
    // xn2 = LN2(y)
    ln_kernel<<<NTOK, blk, 0, stream>>>(y, g2, e2, xnf, xnb);
    // hb = gelu(xn2 @ w1^T + b1)   (bf16 out)
    gemm_bt<1,0,1><<<dim3(HM / 128, NTOK / 128), blk, 0, stream>>>(
        xnb, w1b, b1, nullptr, hb, NTOK, HM, DM);
    // out = xn2 + hb @ w2^T + b2   (fp32 out, 128x64 tiles)
    gemm_n64<0,1,0><<<dim3(DM / 64, NTOK / 128), blk, 0, stream>>>(
        hb, w2b, b2, xnf, d_out, NTOK, DM, HM);
}

// Round 8
// 423.792 us; speedup vs baseline: 20.3211x; 1.0197x over previous
//
#include <hip/hip_runtime.h>
#include <hip/hip_bf16.h>

typedef unsigned short u16;
typedef __attribute__((ext_vector_type(8))) short short8;   // 8 bf16 (4 VGPRs)
typedef __attribute__((ext_vector_type(4))) float f32x4;    // 4 fp32 acc

#define DM 1024      // d_model
#define HM 4096      // ffn hidden
#define NHEADS 16
#define HD 64        // head dim
#define SQ 2048      // seq len
#define NBATCH 2
#define NTOK 4096    // NBATCH*SQ

#define NX  ((size_t)NTOK * DM)

__device__ __forceinline__ u16 f2b(float f) {   // fp32 -> bf16 RNE
    union { float f; unsigned int i; } w; w.f = f;
    unsigned int x = w.i;
    return (u16)((x + 0x7FFFu + ((x >> 16) & 1u)) >> 16);
}
__device__ __forceinline__ u16 f2b_ru(float f) {  // round-half-up (positives)
    union { float f; unsigned int i; } w; w.f = f;
    return (u16)((w.i + 0x8000u) >> 16);
}

__device__ __forceinline__ void gload_lds16(const void* g, void* l) {
    __builtin_amdgcn_global_load_lds(
        (const __attribute__((address_space(1))) void*)g,
        (__attribute__((address_space(3))) void*)l, 16, 0, 0);
}

// ---- all weights fp32 -> bf16 in ONE kernel (dst regions contiguous) ----
// dst layout (u16): wq|wk|wv (3M) | wo (1M) | w1 (4M) | w2 (4M)
__global__ void cvt_all(const float* __restrict__ wq, const float* __restrict__ wk,
                        const float* __restrict__ wv, const float* __restrict__ wo,
                        const float* __restrict__ w1, const float* __restrict__ w2,
                        u16* __restrict__ dst) {
    const int NW4 = DM * DM / 4;   // 262144 float4s per DMxDM matrix
    int i = blockIdx.x * 256 + threadIdx.x;
    if (i >= 12 * NW4) return;
    const float* src; int base; float sc = 1.0f;
    if      (i <     NW4) { src = wq; base = 0;       sc = 0.125f; }
    else if (i < 2 * NW4) { src = wk; base = NW4; }
    else if (i < 3 * NW4) { src = wv; base = 2 * NW4; }
    else if (i < 4 * NW4) { src = wo; base = 3 * NW4; }
    else if (i < 8 * NW4) { src = w1; base = 4 * NW4; }
    else                  { src = w2; base = 8 * NW4; }
    float4 f = ((const float4*)src)[i - base];
    ushort4 o;
    o.x = f2b(f.x * sc); o.y = f2b(f.y * sc);
    o.z = f2b(f.z * sc); o.w = f2b(f.w * sc);
    ((ushort4*)dst)[i] = o;
}

// ---- pack qkv biases (bq scaled by 0.125 to match scaled wq) ----
__global__ void pack_bias(const float* __restrict__ bq, const float* __restrict__ bk,
                          const float* __restrict__ bv, float* __restrict__ dst) {
    int i = blockIdx.x * 256 + threadIdx.x;
    if (i >= 3 * DM) return;
    float v = (i < DM) ? bq[i] * 0.125f : (i < 2 * DM) ? bk[i - DM] : bv[i - 2 * DM];
    dst[i] = v;
}

// ---------------- LayerNorm: fp32 in, fp32 + bf16 out ----------------
__global__ void ln_kernel(const float* __restrict__ xin, const float* __restrict__ g,
                          const float* __restrict__ b, float* __restrict__ outf,
                          u16* __restrict__ outb) {
    int t = blockIdx.x, tid = threadIdx.x;
    float4 f = ((const float4*)(xin + (size_t)t * DM))[tid];
    float v0 = f.x, v1 = f.y, v2 = f.z, v3 = f.w;
    float s  = v0 + v1 + v2 + v3;
    float ss = v0*v0 + v1*v1 + v2*v2 + v3*v3;
    #pragma unroll
    for (int o = 32; o > 0; o >>= 1) {
        s  += __shfl_down(s,  o, 64);
        ss += __shfl_down(ss, o, 64);
    }
    __shared__ float rs[4], rss[4];
    int w = tid >> 6, lane = tid & 63;
    if (!lane) { rs[w] = s; rss[w] = ss; }
    __syncthreads();
    s  = rs[0] + rs[1] + rs[2] + rs[3];
    ss = rss[0] + rss[1] + rss[2] + rss[3];
    float mean = s * (1.0f / DM);
    float var  = ss * (1.0f / DM) - mean * mean;
    float rstd = rsqrtf(var + 1e-5f);
    float4 gu = ((const float4*)g)[tid];
    float4 bu = ((const float4*)b)[tid];
    float4 o;
    o.x = (v0 - mean) * rstd * gu.x + bu.x;
    o.y = (v1 - mean) * rstd * gu.y + bu.y;
    o.z = (v2 - mean) * rstd * gu.z + bu.z;
    o.w = (v3 - mean) * rstd * gu.w + bu.w;
    ((float4*)(outf + (size_t)t * DM))[tid] = o;
    ushort4 ob; ob.x = f2b(o.x); ob.y = f2b(o.y); ob.z = f2b(o.z); ob.w = f2b(o.w);
    ((ushort4*)(outb + (size_t)t * DM))[tid] = ob;
}

// ------- MFMA GEMM 128x128, BK=64: C = A·W^T + bias -------
// Row-major LDS tiles [128][64] u16. 16 segs of 8 rows; wave stages segs 4w..4w+3.
template<int GELU, int RESID, int OUTBF>
__global__ __launch_bounds__(256, 3)
void gemm_bt(const u16* __restrict__ A, const u16* __restrict__ W,
             const float* __restrict__ bias, const float* __restrict__ resid,
             void* __restrict__ Cout, int M, int N, int K) {
    __shared__ __attribute__((aligned(16))) u16 As[128 * 64];   // 16 KB
    __shared__ __attribute__((aligned(16))) u16 Bs[128 * 64];   // 16 KB
    int tid  = threadIdx.x;
    int wid  = tid >> 6, lane = tid & 63;
    int m0 = blockIdx.y << 7, n0 = blockIdx.x << 7;
    int wm = (wid & 1) << 6, wn = (wid >> 1) << 6;

    int rIn = lane >> 3;           // row within 8-row seg
    int cIn = (lane & 7) << 3;     // col (x8 bf16)
    int s0  = wid << 2;
    int fr = lane & 15;
    int fc = (lane >> 4) << 3;

    f32x4 acc[4][4];
    #pragma unroll
    for (int i = 0; i < 4; i++)
        #pragma unroll
        for (int j = 0; j < 4; j++)
            acc[i][j] = (f32x4){0.f, 0.f, 0.f, 0.f};

    for (int k0 = 0; k0 < K; k0 += 64) {
        #pragma unroll
        for (int t = 0; t < 4; t++) {
            int s = s0 + t;
            gload_lds16(A + (size_t)(m0 + (s << 3) + rIn) * K + k0 + cIn, As + (s << 9));
            gload_lds16(W + (size_t)(n0 + (s << 3) + rIn) * K + k0 + cIn, Bs + (s << 9));
        }
        __syncthreads();
        #pragma unroll
        for (int ch = 0; ch < 2; ch++) {
            int kc = (ch << 5) + fc;
            short8 af[4], bf[4];
            #pragma unroll
            for (int mi = 0; mi < 4; mi++)
                af[mi] = *(const short8*)(As + (size_t)(wm + (mi << 4) + fr) * 64 + kc);
            #pragma unroll
            for (int ni = 0; ni < 4; ni++)
                bf[ni] = *(const short8*)(Bs + (size_t)(wn + (ni << 4) + fr) * 64 + kc);
            #pragma unroll
            for (int mi = 0; mi < 4; mi++)
                #pragma unroll
                for (int ni = 0; ni < 4; ni++)
                    acc[mi][ni] = __builtin_amdgcn_mfma_f32_16x16x32_bf16(
                        af[mi], bf[ni], acc[mi][ni], 0, 0, 0);
        }
        __syncthreads();
    }

    int erow = (lane >> 4) << 2;
    #pragma unroll
    for (int ni = 0; ni < 4; ni++) {
        int col = n0 + wn + (ni << 4) + fr;
        float bv = bias[col];
        #pragma unroll
        for (int mi = 0; mi < 4; mi++) {
            #pragma unroll
            for (int r = 0; r < 4; r++) {
                int row = m0 + wm + (mi << 4) + erow + r;
                float val = acc[mi][ni][r] + bv;
                if (GELU)  val = 0.5f * val * (1.0f + erff(val * 0.70710678118654752f));
                if (RESID) val += resid[(size_t)row * N + col];
                if (OUTBF) ((u16*)Cout)[(size_t)row * N + col] = f2b(val);
                else       ((float*)Cout)[(size_t)row * N + col] = val;
            }
        }
    }
}

// ------- MFMA GEMM 128x64, BK=64 (N=1024 outputs: 512 blocks) -------
template<int GELU, int RESID, int OUTBF>
__global__ __launch_bounds__(256, 3)
void gemm_n64(const u16* __restrict__ A, const u16* __restrict__ W,
              const float* __restrict__ bias, const float* __restrict__ resid,
              void* __restrict__ Cout, int M, int N, int K) {
    __shared__ __attribute__((aligned(16))) u16 As[128 * 64];   // 16 KB
    __shared__ __attribute__((aligned(16))) u16 Bs[64 * 64];    // 8 KB
    int tid  = threadIdx.x;
    int wid  = tid >> 6, lane = tid & 63;
    int m0 = blockIdx.y << 7, n0 = blockIdx.x << 6;
    int wm = (wid & 1) << 6, wn = (wid >> 1) << 5;

    int rIn = lane >> 3;
    int cIn = (lane & 7) << 3;
    int sA = wid << 2;        // A segs 4w..4w+3 (16 total)
    int sB = wid << 1;        // B segs 2w, 2w+1 (8 total)
    int fr = lane & 15;
    int fc = (lane >> 4) << 3;

    f32x4 acc[4][2];
    #pragma unroll
    for (int i = 0; i < 4; i++)
        #pragma unroll
        for (int j = 0; j < 2; j++)
            acc[i][j] = (f32x4){0.f, 0.f, 0.f, 0.f};

    for (int k0 = 0; k0 < K; k0 += 64) {
        #pragma unroll
        for (int t = 0; t < 4; t++) {
            int s = sA + t;
            gload_lds16(A + (size_t)(m0 + (s << 3) + rIn) * K + k0 + cIn, As + (s << 9));
        }
        #pragma unroll
        for (int t = 0; t < 2; t++) {
            int s = sB + t;
            gload_lds16(W + (size_t)(n0 + (s << 3) + rIn) * K + k0 + cIn, Bs + (s << 9));
        }
        __syncthreads();
        #pragma unroll
        for (int ch = 0; ch < 2; ch++) {
            int kc = (ch << 5) + fc;
            short8 af[4], bf[2];
            #pragma unroll
            for (int mi = 0; mi < 4; mi++)
                af[mi] = *(const short8*)(As + (size_t)(wm + (mi << 4) + fr) * 64 + kc);
            #pragma unroll
            for (int ni = 0; ni < 2; ni++)
                bf[ni] = *(const short8*)(Bs + (size_t)(wn + (ni << 4) + fr) * 64 + kc);
            #pragma unroll
            for (int mi = 0; mi < 4; mi++)
                #pragma unroll
                for (int ni = 0; ni < 2; ni++)
                    acc[mi][ni] = __builtin_amdgcn_mfma_f32_16x16x32_bf16(
                        af[mi], bf[ni], acc[mi][ni], 0, 0, 0);
        }
        __syncthreads();
    }

    int erow = (lane >> 4) << 2;
    #pragma unroll
    for (int ni = 0; ni < 2; ni++) {
        int col = n0 + wn + (ni << 4) + fr;
        float bv = bias[col];
        #pragma unroll
        for (int mi = 0; mi < 4; mi++) {
            #pragma unroll
            for (int r = 0; r < 4; r++) {
                int row = m0 + wm + (mi << 4) + erow + r;
                float val = acc[mi][ni][r] + bv;
                if (GELU)  val = 0.5f * val * (1.0f + erff(val * 0.70710678118654752f));
                if (RESID) val += resid[(size_t)row * N + col];
                if (OUTBF) ((u16*)Cout)[(size_t)row * N + col] = f2b(val);
                else       ((float*)Cout)[(size_t)row * N + col] = val;
            }
        }
    }
}

// ---------------- MFMA flash attention v3: Qs/Ps union, 40 KB LDS ----------------
__global__ __launch_bounds__(256) void fattn_mfma(const u16* __restrict__ QKV,
                                                  u16* __restrict__ O) {
    __shared__ __attribute__((aligned(16))) u16 QP[4096];        // Q then per-wave Ps
    __shared__ __attribute__((aligned(16))) u16 Ks[2][4096];     // dbuf [2ch][64][32]
    __shared__ __attribute__((aligned(16))) u16 Vt[2][4096];     // dbuf [2ch][64d][32k]
    const int ld = 3 * DM;
    int bid = blockIdx.x;
    int qt = bid & 31, bh = bid >> 5;
    int h = bh & (NHEADS - 1), b = bh >> 4;
    int tid = threadIdx.x, wid = tid >> 6, lane = tid & 63;
    int fr = lane & 15, fc = (lane >> 4) << 3;
    size_t tokb = (size_t)b * SQ;
    const u16* Qg = QKV + tokb * ld + h * HD;
    const u16* Kg = QKV + tokb * ld + DM + h * HD;
    const u16* Vg = QKV + tokb * ld + 2 * DM + h * HD;
    int vk = lane, vd0 = wid << 4;
    int s0 = wid << 1;
    u16* Ps = QP + (wid << 10);   // wave-private 1 KB slab (A-frag chunked [2][16][32])

    {   // stage Q tile into QP (seg s: chunk s>>2, rows (s&3)*16)
        #pragma unroll
        for (int t = 0; t < 2; t++) {
            int s = s0 + t;
            const u16* g = Qg + (size_t)(qt * 64 + ((s & 3) << 4) + (lane >> 2)) * ld
                         + ((s >> 2) << 5) + ((lane & 3) << 3);
            gload_lds16(g, QP + (s << 9));
        }
    }
    {   // stage K/V tile 0 into buf 0
        #pragma unroll
        for (int t = 0; t < 2; t++) {
            int s = s0 + t;
            const u16* g = Kg + (size_t)(((s & 3) << 4) + (lane >> 2)) * ld
                         + ((s >> 2) << 5) + ((lane & 3) << 3);
            gload_lds16(g, Ks[0] + (s << 9));
        }
        const u16* vrow = Vg + (size_t)vk * ld + vd0;
        int cbase = (vk >> 5) << 11;
        int kk = vk & 31;
        #pragma unroll
        for (int j = 0; j < 4; j++) {
            ushort4 vv = *(const ushort4*)(vrow + (j << 2));
            int d = vd0 + (j << 2);
            Vt[0][cbase + (d + 0) * 32 + kk] = vv.x;
            Vt[0][cbase + (d + 1) * 32 + kk] = vv.y;
            Vt[0][cbase + (d + 2) * 32 + kk] = vv.z;
            Vt[0][cbase + (d + 3) * 32 + kk] = vv.w;
        }
    }
    f32x4 oacc[4];
    #pragma unroll
    for (int di = 0; di < 4; di++) oacc[di] = (f32x4){0.f, 0.f, 0.f, 0.f};
    float lsum[4] = {0.f, 0.f, 0.f, 0.f};
    __syncthreads();   // Q + tile0 visible
    short8 aq0 = *(const short8*)(QP + ((wid << 4) + fr) * 32 + fc);
    short8 aq1 = *(const short8*)(QP + 2048 + ((wid << 4) + fr) * 32 + fc);
    __syncthreads();   // all waves hold Q frags before QP is reused as Ps

    for (int kt = 0; kt < SQ / 64; kt++) {
        int buf = kt & 1;
        if (kt + 1 < SQ / 64) {   // prefetch next tile into buf^1
            #pragma unroll
            for (int t = 0; t < 2; t++) {
                int s = s0 + t;
                const u16* g = Kg + (size_t)((kt + 1) * 64 + ((s & 3) << 4) + (lane >> 2)) * ld
                             + ((s >> 2) << 5) + ((lane & 3) << 3);
                gload_lds16(g, Ks[buf ^ 1] + (s << 9));
            }
            const u16* vrow = Vg + (size_t)((kt + 1) * 64 + vk) * ld + vd0;
            int cbase = (vk >> 5) << 11;
            int kk = vk & 31;
            #pragma unroll
            for (int j = 0; j < 4; j++) {
                ushort4 vv = *(const ushort4*)(vrow + (j << 2));
                int d = vd0 + (j << 2);
                Vt[buf ^ 1][cbase + (d + 0) * 32 + kk] = vv.x;
                Vt[buf ^ 1][cbase + (d + 1) * 32 + kk] = vv.y;
                Vt[buf ^ 1][cbase + (d + 2) * 32 + kk] = vv.z;
                Vt[buf ^ 1][cbase + (d + 3) * 32 + kk] = vv.w;
            }
        }
        // S = Q K^T ; P = exp(S) -> Ps (0.125 pre-folded into wq/bq)
        #pragma unroll
        for (int ni = 0; ni < 4; ni++) {
            short8 bk0 = *(const short8*)(Ks[buf] + ((ni << 4) + fr) * 32 + fc);
            short8 bk1 = *(const short8*)(Ks[buf] + 2048 + ((ni << 4) + fr) * 32 + fc);
            f32x4 z = (f32x4){0.f, 0.f, 0.f, 0.f};
            z = __builtin_amdgcn_mfma_f32_16x16x32_bf16(aq0, bk0, z, 0, 0, 0);
            z = __builtin_amdgcn_mfma_f32_16x16x32_bf16(aq1, bk1, z, 0, 0, 0);
            int c  = (ni << 4) + fr;
            int cb = (c >> 5) << 9;
            int kk = c & 31;
            #pragma unroll
            for (int r = 0; r < 4; r++) {
                float e = __expf(z[r]);
                lsum[r] += e;
                Ps[cb + (((lane >> 4) << 2) + r) * 32 + kk] = f2b_ru(e);
            }
        }
        // O += P V
        short8 ap0 = *(const short8*)(Ps + fr * 32 + fc);
        short8 ap1 = *(const short8*)(Ps + 512 + fr * 32 + fc);
        #pragma unroll
        for (int di = 0; di < 4; di++) {
            short8 bv0 = *(const short8*)(Vt[buf] + ((di << 4) + fr) * 32 + fc);
            short8 bv1 = *(const short8*)(Vt[buf] + 2048 + ((di << 4) + fr) * 32 + fc);
            oacc[di] = __builtin_amdgcn_mfma_f32_16x16x32_bf16(ap0, bv0, oacc[di], 0, 0, 0);
            oacc[di] = __builtin_amdgcn_mfma_f32_16x16x32_bf16(ap1, bv1, oacc[di], 0, 0, 0);
        }
        __syncthreads();   // drain prefetch; protect buf swap
    }
    #pragma unroll
    for (int msk = 1; msk <= 8; msk <<= 1)
        #pragma unroll
        for (int r = 0; r < 4; r++) lsum[r] += __shfl_xor(lsum[r], msk, 64);
    float inv[4];
    #pragma unroll
    for (int r = 0; r < 4; r++) inv[r] = 1.0f / lsum[r];
    #pragma unroll
    for (int di = 0; di < 4; di++) {
        int d = (di << 4) + fr;
        #pragma unroll
        for (int r = 0; r < 4; r++) {
            int q = qt * 64 + (wid << 4) + ((lane >> 4) << 2) + r;
            O[(tokb + q) * DM + h * HD + d] = f2b(oacc[di][r] * inv[r]);
        }
    }
}

extern "C" void kernel_launch(void* const* d_in, const int* in_sizes, int n_in,
                              void* d_out, int out_size, void* d_ws, size_t ws_size,
                              hipStream_t stream) {
    if (n_in < 17) return;
    const float* x   = (const float*)d_in[0];
    const float* wq  = (const float*)d_in[1];
    const float* bq  = (const float*)d_in[2];
    const float* wk  = (const float*)d_in[3];
    const float* bk  = (const float*)d_in[4];
    const float* wv  = (const float*)d_in[5];
    const float* bv  = (const float*)d_in[6];
    const float* wo  = (const float*)d_in[7];
    const float* bo  = (const float*)d_in[8];
    const float* g1  = (const float*)d_in[9];
    const float* e1  = (const float*)d_in[10];
    const float* w1  = (const float*)d_in[11];
    const float* b1  = (const float*)d_in[12];
    const float* w2  = (const float*)d_in[13];
    const float* b2  = (const float*)d_in[14];
    const float* g2  = (const float*)d_in[15];
    const float* e2  = (const float*)d_in[16];

    float* F = (float*)d_ws;
    size_t off = 0;
    float* xnf   = F + off; off += NX;
    u16*   xnb   = (u16*)(F + off); off += NX / 2;
    u16*   qkvb  = (u16*)(F + off); off += (size_t)NTOK * 3 * DM / 2;
    float* y     = F + off; off += NX;
    u16*   aob   = (u16*)(F + off); off += NX / 2;
    u16*   hb    = (u16*)(F + off); off += (size_t)NTOK * HM / 2;
    // weight region: wqkv | wo | w1 | w2 contiguous (12M u16)
    u16*   wqkvb = (u16*)(F + off); off += (size_t)3 * DM * DM / 2;
    u16*   wob   = (u16*)(F + off); off += (size_t)DM * DM / 2;
    u16*   w1b   = (u16*)(F + off); off += (size_t)HM * DM / 2;
    u16*   w2b   = (u16*)(F + off); off += (size_t)DM * HM / 2;
    float* bqkv  = F + off; off += 3 * DM;
    if (ws_size < off * sizeof(float)) return;

    dim3 blk(256);
    cvt_all<<<(12 * DM * DM / 4 + 255) / 256, blk, 0, stream>>>(
        wq, wk, wv, wo, w1, w2, wqkvb);
    pack_bias<<<(3 * DM + 255) / 256, blk, 0, stream>>>(bq, bk, bv, bqkv);

    // xn1 = LN1(x)
    ln_kernel<<<NTOK, blk, 0, stream>>>(x, g1, e1, xnf, xnb);
    // qkv = xn1 @ [0.125wq|wk|wv]^T + b   (bf16 out)
    gemm_bt<0,0,1><<<dim3(3 * DM / 128, NTOK / 128), blk, 0, stream>>>(
        xnb, wqkvb, bqkv, nullptr, qkvb, NTOK, 3 * DM, DM);
    // aob = softmax(q k^T) v
    fattn_mfma<<<NBATCH * NHEADS * (SQ / 64), blk, 0, stream>>>(qkvb, aob);
    // y = xn1 + aob @ wo^T + bo
    gemm_n64<0,1,0><<<dim3(DM / 64, NTOK / 128), blk, 0, stream>>>(
        aob, wob, bo, xnf, y, NTOK, DM, DM);
    // xn2 = LN2(y)
    ln_kernel<<<NTOK, blk, 0, stream>>>(y, g2, e2, xnf, xnb);
    // hb = gelu(xn2 @ w1^T + b1)   (bf16 out)
    gemm_bt<1,0,1><<<dim3(HM / 128, NTOK / 128), blk, 0, stream>>>(
        xnb, w1b, b1, nullptr, hb, NTOK, HM, DM);
    // out = xn2 + hb @ w2^T + b2   (fp32 out)
    gemm_n64<0,1,0><<<dim3(DM / 64, NTOK / 128), blk, 0, stream>>>(
        hb, w2b, b2, xnf, d_out, NTOK, DM, HM);
}

// Round 9
// 419.021 us; speedup vs baseline: 20.5525x; 1.0114x over previous
//
#include <hip/hip_runtime.h>
#include <hip/hip_bf16.h>

typedef unsigned short u16;
typedef __attribute__((ext_vector_type(8))) short short8;   // 8 bf16 (4 VGPRs)
typedef __attribute__((ext_vector_type(4))) float f32x4;    // 4 fp32 acc

#define DM 1024      // d_model
#define HM 4096      // ffn hidden
#define NHEADS 16
#define HD 64        // head dim
#define SQ 2048      // seq len
#define NBATCH 2
#define NTOK 4096    // NBATCH*SQ

#define NX  ((size_t)NTOK * DM)

__device__ __forceinline__ u16 f2b(float f) {   // fp32 -> bf16 RNE
    union { float f; unsigned int i; } w; w.f = f;
    unsigned int x = w.i;
    return (u16)((x + 0x7FFFu + ((x >> 16) & 1u)) >> 16);
}
__device__ __forceinline__ u16 f2b_ru(float f) {  // round-half-up (positives)
    union { float f; unsigned int i; } w; w.f = f;
    return (u16)((w.i + 0x8000u) >> 16);
}

__device__ __forceinline__ void gload_lds16(const void* g, void* l) {
    __builtin_amdgcn_global_load_lds(
        (const __attribute__((address_space(1))) void*)g,
        (__attribute__((address_space(3))) void*)l, 16, 0, 0);
}

// ---- all weights fp32 -> bf16 + bias pack, ONE kernel ----
// dst layout (u16): wq|wk|wv (3M) | wo (1M) | w1 (4M) | w2 (4M)
__global__ void cvt_all(const float* __restrict__ wq, const float* __restrict__ wk,
                        const float* __restrict__ wv, const float* __restrict__ wo,
                        const float* __restrict__ w1, const float* __restrict__ w2,
                        const float* __restrict__ bq, const float* __restrict__ bk,
                        const float* __restrict__ bv, float* __restrict__ bias_dst,
                        u16* __restrict__ dst) {
    const int NW4 = DM * DM / 4;   // float4s per DMxDM matrix
    int i = blockIdx.x * 256 + threadIdx.x;
    if (i < 12 * NW4) {
        const float* src; int base; float sc = 1.0f;
        if      (i <     NW4) { src = wq; base = 0;       sc = 0.125f; }
        else if (i < 2 * NW4) { src = wk; base = NW4; }
        else if (i < 3 * NW4) { src = wv; base = 2 * NW4; }
        else if (i < 4 * NW4) { src = wo; base = 3 * NW4; }
        else if (i < 8 * NW4) { src = w1; base = 4 * NW4; }
        else                  { src = w2; base = 8 * NW4; }
        float4 f = ((const float4*)src)[i - base];
        ushort4 o;
        o.x = f2b(f.x * sc); o.y = f2b(f.y * sc);
        o.z = f2b(f.z * sc); o.w = f2b(f.w * sc);
        ((ushort4*)dst)[i] = o;
    } else {
        int j = i - 12 * NW4;
        if (j < 3 * DM) {
            float v = (j < DM) ? bq[j] * 0.125f
                    : (j < 2 * DM) ? bk[j - DM] : bv[j - 2 * DM];
            bias_dst[j] = v;
        }
    }
}

// ---------------- LayerNorm: fp32 in, fp32 + bf16 out ----------------
__global__ void ln_kernel(const float* __restrict__ xin, const float* __restrict__ g,
                          const float* __restrict__ b, float* __restrict__ outf,
                          u16* __restrict__ outb) {
    int t = blockIdx.x, tid = threadIdx.x;
    float4 f = ((const float4*)(xin + (size_t)t * DM))[tid];
    float v0 = f.x, v1 = f.y, v2 = f.z, v3 = f.w;
    float s  = v0 + v1 + v2 + v3;
    float ss = v0*v0 + v1*v1 + v2*v2 + v3*v3;
    #pragma unroll
    for (int o = 32; o > 0; o >>= 1) {
        s  += __shfl_down(s,  o, 64);
        ss += __shfl_down(ss, o, 64);
    }
    __shared__ float rs[4], rss[4];
    int w = tid >> 6, lane = tid & 63;
    if (!lane) { rs[w] = s; rss[w] = ss; }
    __syncthreads();
    s  = rs[0] + rs[1] + rs[2] + rs[3];
    ss = rss[0] + rss[1] + rss[2] + rss[3];
    float mean = s * (1.0f / DM);
    float var  = ss * (1.0f / DM) - mean * mean;
    float rstd = rsqrtf(var + 1e-5f);
    float4 gu = ((const float4*)g)[tid];
    float4 bu = ((const float4*)b)[tid];
    float4 o;
    o.x = (v0 - mean) * rstd * gu.x + bu.x;
    o.y = (v1 - mean) * rstd * gu.y + bu.y;
    o.z = (v2 - mean) * rstd * gu.z + bu.z;
    o.w = (v3 - mean) * rstd * gu.w + bu.w;
    ((float4*)(outf + (size_t)t * DM))[tid] = o;
    ushort4 ob; ob.x = f2b(o.x); ob.y = f2b(o.y); ob.z = f2b(o.z); ob.w = f2b(o.w);
    ((ushort4*)(outb + (size_t)t * DM))[tid] = ob;
}

// ---- V transpose: qkv V-region [tok][h*64+d] -> vT[b*16+h][d][tok_in_batch] ----
__global__ void vtr_kernel(const u16* __restrict__ qkv, u16* __restrict__ vT) {
    __shared__ u16 tile[64][72];
    int bid = blockIdx.x;          // 32 bh x 32 t-tiles
    int tt = bid & 31, bh = bid >> 5;
    int h = bh & (NHEADS - 1), b = bh >> 4;
    int tid = threadIdx.x;
    int r = tid >> 2, c0 = (tid & 3) << 4;
    const u16* src = qkv + ((size_t)(b * SQ + tt * 64 + r)) * (3 * DM) + 2 * DM + h * HD + c0;
    #pragma unroll
    for (int j = 0; j < 4; j++)
        *(ushort4*)&tile[r][c0 + (j << 2)] = *(const ushort4*)(src + (j << 2));
    __syncthreads();
    int dd = tid >> 2, t0 = (tid & 3) << 4;
    u16* dst = vT + ((size_t)bh * HD + dd) * SQ + tt * 64 + t0;
    #pragma unroll
    for (int j = 0; j < 4; j++) {
        ushort4 v;
        v.x = tile[t0 + (j << 2) + 0][dd];
        v.y = tile[t0 + (j << 2) + 1][dd];
        v.z = tile[t0 + (j << 2) + 2][dd];
        v.w = tile[t0 + (j << 2) + 3][dd];
        *(ushort4*)(dst + (j << 2)) = v;
    }
}

// ------- MFMA GEMM 128x128, BK=64: C = A·W^T + bias -------
template<int GELU, int RESID, int OUTBF>
__global__ __launch_bounds__(256, 3)
void gemm_bt(const u16* __restrict__ A, const u16* __restrict__ W,
             const float* __restrict__ bias, const float* __restrict__ resid,
             void* __restrict__ Cout, int M, int N, int K) {
    __shared__ __attribute__((aligned(16))) u16 As[128 * 64];   // 16 KB
    __shared__ __attribute__((aligned(16))) u16 Bs[128 * 64];   // 16 KB
    int tid  = threadIdx.x;
    int wid  = tid >> 6, lane = tid & 63;
    int m0 = blockIdx.y << 7, n0 = blockIdx.x << 7;
    int wm = (wid & 1) << 6, wn = (wid >> 1) << 6;

    int rIn = lane >> 3;
    int cIn = (lane & 7) << 3;
    int s0  = wid << 2;
    int fr = lane & 15;
    int fc = (lane >> 4) << 3;

    f32x4 acc[4][4];
    #pragma unroll
    for (int i = 0; i < 4; i++)
        #pragma unroll
        for (int j = 0; j < 4; j++)
            acc[i][j] = (f32x4){0.f, 0.f, 0.f, 0.f};

    for (int k0 = 0; k0 < K; k0 += 64) {
        #pragma unroll
        for (int t = 0; t < 4; t++) {
            int s = s0 + t;
            gload_lds16(A + (size_t)(m0 + (s << 3) + rIn) * K + k0 + cIn, As + (s << 9));
            gload_lds16(W + (size_t)(n0 + (s << 3) + rIn) * K + k0 + cIn, Bs + (s << 9));
        }
        __syncthreads();
        #pragma unroll
        for (int ch = 0; ch < 2; ch++) {
            int kc = (ch << 5) + fc;
            short8 af[4], bf[4];
            #pragma unroll
            for (int mi = 0; mi < 4; mi++)
                af[mi] = *(const short8*)(As + (size_t)(wm + (mi << 4) + fr) * 64 + kc);
            #pragma unroll
            for (int ni = 0; ni < 4; ni++)
                bf[ni] = *(const short8*)(Bs + (size_t)(wn + (ni << 4) + fr) * 64 + kc);
            #pragma unroll
            for (int mi = 0; mi < 4; mi++)
                #pragma unroll
                for (int ni = 0; ni < 4; ni++)
                    acc[mi][ni] = __builtin_amdgcn_mfma_f32_16x16x32_bf16(
                        af[mi], bf[ni], acc[mi][ni], 0, 0, 0);
        }
        __syncthreads();
    }

    int erow = (lane >> 4) << 2;
    #pragma unroll
    for (int ni = 0; ni < 4; ni++) {
        int col = n0 + wn + (ni << 4) + fr;
        float bv = bias[col];
        #pragma unroll
        for (int mi = 0; mi < 4; mi++) {
            #pragma unroll
            for (int r = 0; r < 4; r++) {
                int row = m0 + wm + (mi << 4) + erow + r;
                float val = acc[mi][ni][r] + bv;
                if (GELU)  val = 0.5f * val * (1.0f + erff(val * 0.70710678118654752f));
                if (RESID) val += resid[(size_t)row * N + col];
                if (OUTBF) ((u16*)Cout)[(size_t)row * N + col] = f2b(val);
                else       ((float*)Cout)[(size_t)row * N + col] = val;
            }
        }
    }
}

// ------- MFMA GEMM 128x64, BK=64 (N=1024 outputs: 512 blocks) -------
template<int GELU, int RESID, int OUTBF>
__global__ __launch_bounds__(256, 3)
void gemm_n64(const u16* __restrict__ A, const u16* __restrict__ W,
              const float* __restrict__ bias, const float* __restrict__ resid,
              void* __restrict__ Cout, int M, int N, int K) {
    __shared__ __attribute__((aligned(16))) u16 As[128 * 64];   // 16 KB
    __shared__ __attribute__((aligned(16))) u16 Bs[64 * 64];    // 8 KB
    int tid  = threadIdx.x;
    int wid  = tid >> 6, lane = tid & 63;
    int m0 = blockIdx.y << 7, n0 = blockIdx.x << 6;
    int wm = (wid & 1) << 6, wn = (wid >> 1) << 5;

    int rIn = lane >> 3;
    int cIn = (lane & 7) << 3;
    int sA = wid << 2;
    int sB = wid << 1;
    int fr = lane & 15;
    int fc = (lane >> 4) << 3;

    f32x4 acc[4][2];
    #pragma unroll
    for (int i = 0; i < 4; i++)
        #pragma unroll
        for (int j = 0; j < 2; j++)
            acc[i][j] = (f32x4){0.f, 0.f, 0.f, 0.f};

    for (int k0 = 0; k0 < K; k0 += 64) {
        #pragma unroll
        for (int t = 0; t < 4; t++) {
            int s = sA + t;
            gload_lds16(A + (size_t)(m0 + (s << 3) + rIn) * K + k0 + cIn, As + (s << 9));
        }
        #pragma unroll
        for (int t = 0; t < 2; t++) {
            int s = sB + t;
            gload_lds16(W + (size_t)(n0 + (s << 3) + rIn) * K + k0 + cIn, Bs + (s << 9));
        }
        __syncthreads();
        #pragma unroll
        for (int ch = 0; ch < 2; ch++) {
            int kc = (ch << 5) + fc;
            short8 af[4], bf[2];
            #pragma unroll
            for (int mi = 0; mi < 4; mi++)
                af[mi] = *(const short8*)(As + (size_t)(wm + (mi << 4) + fr) * 64 + kc);
            #pragma unroll
            for (int ni = 0; ni < 2; ni++)
                bf[ni] = *(const short8*)(Bs + (size_t)(wn + (ni << 4) + fr) * 64 + kc);
            #pragma unroll
            for (int mi = 0; mi < 4; mi++)
                #pragma unroll
                for (int ni = 0; ni < 2; ni++)
                    acc[mi][ni] = __builtin_amdgcn_mfma_f32_16x16x32_bf16(
                        af[mi], bf[ni], acc[mi][ni], 0, 0, 0);
        }
        __syncthreads();
    }

    int erow = (lane >> 4) << 2;
    #pragma unroll
    for (int ni = 0; ni < 2; ni++) {
        int col = n0 + wn + (ni << 4) + fr;
        float bv = bias[col];
        #pragma unroll
        for (int mi = 0; mi < 4; mi++) {
            #pragma unroll
            for (int r = 0; r < 4; r++) {
                int row = m0 + wm + (mi << 4) + erow + r;
                float val = acc[mi][ni][r] + bv;
                if (GELU)  val = 0.5f * val * (1.0f + erff(val * 0.70710678118654752f));
                if (RESID) val += resid[(size_t)row * N + col];
                if (OUTBF) ((u16*)Cout)[(size_t)row * N + col] = f2b(val);
                else       ((float*)Cout)[(size_t)row * N + col] = val;
            }
        }
    }
}

// ---------------- MFMA flash attention v4: V pre-transposed globally ----------------
__global__ __launch_bounds__(256) void fattn_mfma(const u16* __restrict__ QKV,
                                                  const u16* __restrict__ VT,
                                                  u16* __restrict__ O) {
    __shared__ __attribute__((aligned(16))) u16 QP[4096];        // Q then per-wave Ps
    __shared__ __attribute__((aligned(16))) u16 Ks[2][4096];     // dbuf [2ch][64][32]
    __shared__ __attribute__((aligned(16))) u16 Vt[2][4096];     // dbuf [2ch][64d][32k]
    const int ld = 3 * DM;
    int bid = blockIdx.x;
    int qt = bid & 31, bh = bid >> 5;
    int h = bh & (NHEADS - 1), b = bh >> 4;
    int tid = threadIdx.x, wid = tid >> 6, lane = tid & 63;
    int fr = lane & 15, fc = (lane >> 4) << 3;
    size_t tokb = (size_t)b * SQ;
    const u16* Qg  = QKV + tokb * ld + h * HD;
    const u16* Kg  = QKV + tokb * ld + DM + h * HD;
    const u16* VTg = VT + ((size_t)bh * HD) * SQ;   // [d][tok]
    int s0 = wid << 1;
    u16* Ps = QP + (wid << 10);   // wave-private 1 KB slab

    {   // stage Q tile (seg s: chunk s>>2, rows (s&3)*16)
        #pragma unroll
        for (int t = 0; t < 2; t++) {
            int s = s0 + t;
            const u16* g = Qg + (size_t)(qt * 64 + ((s & 3) << 4) + (lane >> 2)) * ld
                         + ((s >> 2) << 5) + ((lane & 3) << 3);
            gload_lds16(g, QP + (s << 9));
        }
    }
    {   // stage K/V tile 0 into buf 0
        #pragma unroll
        for (int t = 0; t < 2; t++) {
            int s = s0 + t;
            const u16* g = Kg + (size_t)(((s & 3) << 4) + (lane >> 2)) * ld
                         + ((s >> 2) << 5) + ((lane & 3) << 3);
            gload_lds16(g, Ks[0] + (s << 9));
            const u16* gv = VTg + (size_t)(((s & 3) << 4) + (lane >> 2)) * SQ
                          + ((s >> 2) << 5) + ((lane & 3) << 3);
            gload_lds16(gv, Vt[0] + (s << 9));
        }
    }
    f32x4 oacc[4];
    #pragma unroll
    for (int di = 0; di < 4; di++) oacc[di] = (f32x4){0.f, 0.f, 0.f, 0.f};
    float lsum[4] = {0.f, 0.f, 0.f, 0.f};
    __syncthreads();   // Q + tile0 visible
    short8 aq0 = *(const short8*)(QP + ((wid << 4) + fr) * 32 + fc);
    short8 aq1 = *(const short8*)(QP + 2048 + ((wid << 4) + fr) * 32 + fc);
    __syncthreads();   // all waves hold Q frags before QP is reused as Ps

    for (int kt = 0; kt < SQ / 64; kt++) {
        int buf = kt & 1;
        if (kt + 1 < SQ / 64) {   // prefetch next K/V tile into buf^1
            #pragma unroll
            for (int t = 0; t < 2; t++) {
                int s = s0 + t;
                const u16* g = Kg + (size_t)((kt + 1) * 64 + ((s & 3) << 4) + (lane >> 2)) * ld
                             + ((s >> 2) << 5) + ((lane & 3) << 3);
                gload_lds16(g, Ks[buf ^ 1] + (s << 9));
                const u16* gv = VTg + (size_t)(((s & 3) << 4) + (lane >> 2)) * SQ
                              + (kt + 1) * 64 + ((s >> 2) << 5) + ((lane & 3) << 3);
                gload_lds16(gv, Vt[buf ^ 1] + (s << 9));
            }
        }
        // S = Q K^T ; P = exp(S) -> Ps (0.125 pre-folded into wq/bq)
        #pragma unroll
        for (int ni = 0; ni < 4; ni++) {
            short8 bk0 = *(const short8*)(Ks[buf] + ((ni << 4) + fr) * 32 + fc);
            short8 bk1 = *(const short8*)(Ks[buf] + 2048 + ((ni << 4) + fr) * 32 + fc);
            f32x4 z = (f32x4){0.f, 0.f, 0.f, 0.f};
            z = __builtin_amdgcn_mfma_f32_16x16x32_bf16(aq0, bk0, z, 0, 0, 0);
            z = __builtin_amdgcn_mfma_f32_16x16x32_bf16(aq1, bk1, z, 0, 0, 0);
            int c  = (ni << 4) + fr;
            int cb = (c >> 5) << 9;
            int kk = c & 31;
            #pragma unroll
            for (int r = 0; r < 4; r++) {
                float e = __expf(z[r]);
                lsum[r] += e;
                Ps[cb + (((lane >> 4) << 2) + r) * 32 + kk] = f2b_ru(e);
            }
        }
        // O += P V
        short8 ap0 = *(const short8*)(Ps + fr * 32 + fc);
        short8 ap1 = *(const short8*)(Ps + 512 + fr * 32 + fc);
        #pragma unroll
        for (int di = 0; di < 4; di++) {
            short8 bv0 = *(const short8*)(Vt[buf] + ((di << 4) + fr) * 32 + fc);
            short8 bv1 = *(const short8*)(Vt[buf] + 2048 + ((di << 4) + fr) * 32 + fc);
            oacc[di] = __builtin_amdgcn_mfma_f32_16x16x32_bf16(ap0, bv0, oacc[di], 0, 0, 0);
            oacc[di] = __builtin_amdgcn_mfma_f32_16x16x32_bf16(ap1, bv1, oacc[di], 0, 0, 0);
        }
        __syncthreads();   // drain prefetch; protect buf swap
    }
    #pragma unroll
    for (int msk = 1; msk <= 8; msk <<= 1)
        #pragma unroll
        for (int r = 0; r < 4; r++) lsum[r] += __shfl_xor(lsum[r], msk, 64);
    float inv[4];
    #pragma unroll
    for (int r = 0; r < 4; r++) inv[r] = 1.0f / lsum[r];
    #pragma unroll
    for (int di = 0; di < 4; di++) {
        int d = (di << 4) + fr;
        #pragma unroll
        for (int r = 0; r < 4; r++) {
            int q = qt * 64 + (wid << 4) + ((lane >> 4) << 2) + r;
            O[(tokb + q) * DM + h * HD + d] = f2b(oacc[di][r] * inv[r]);
        }
    }
}

extern "C" void kernel_launch(void* const* d_in, const int* in_sizes, int n_in,
                              void* d_out, int out_size, void* d_ws, size_t ws_size,
                              hipStream_t stream) {
    if (n_in < 17) return;
    const float* x   = (const float*)d_in[0];
    const float* wq  = (const float*)d_in[1];
    const float* bq  = (const float*)d_in[2];
    const float* wk  = (const float*)d_in[3];
    const float* bk  = (const float*)d_in[4];
    const float* wv  = (const float*)d_in[5];
    const float* bv  = (const float*)d_in[6];
    const float* wo  = (const float*)d_in[7];
    const float* bo  = (const float*)d_in[8];
    const float* g1  = (const float*)d_in[9];
    const float* e1  = (const float*)d_in[10];
    const float* w1  = (const float*)d_in[11];
    const float* b1  = (const float*)d_in[12];
    const float* w2  = (const float*)d_in[13];
    const float* b2  = (const float*)d_in[14];
    const float* g2  = (const float*)d_in[15];
    const float* e2  = (const float*)d_in[16];

    float* F = (float*)d_ws;
    size_t off = 0;
    float* xnf   = F + off; off += NX;
    u16*   xnb   = (u16*)(F + off); off += NX / 2;
    u16*   qkvb  = (u16*)(F + off); off += (size_t)NTOK * 3 * DM / 2;
    u16*   vTb   = (u16*)(F + off); off += (size_t)NTOK * DM / 2;   // vT[bh][d][tok]
    float* y     = F + off; off += NX;
    u16*   aob   = (u16*)(F + off); off += NX / 2;
    u16*   hb    = (u16*)(F + off); off += (size_t)NTOK * HM / 2;
    u16*   wqkvb = (u16*)(F + off); off += (size_t)3 * DM * DM / 2;
    u16*   wob   = (u16*)(F + off); off += (size_t)DM * DM / 2;
    u16*   w1b   = (u16*)(F + off); off += (size_t)HM * DM / 2;
    u16*   w2b   = (u16*)(F + off); off += (size_t)DM * HM / 2;
    float* bqkv  = F + off; off += 3 * DM;
    if (ws_size < off * sizeof(float)) return;

    dim3 blk(256);
    cvt_all<<<(12 * DM * DM / 4 + 3 * DM + 255) / 256, blk, 0, stream>>>(
        wq, wk, wv, wo, w1, w2, bq, bk, bv, bqkv, wqkvb);

    // xn1 = LN1(x)
    ln_kernel<<<NTOK, blk, 0, stream>>>(x, g1, e1, xnf, xnb);
    // qkv = xn1 @ [0.125wq|wk|wv]^T + b   (bf16 out)
    gemm_bt<0,0,1><<<dim3(3 * DM / 128, NTOK / 128), blk, 0, stream>>>(
        xnb, wqkvb, bqkv, nullptr, qkvb, NTOK, 3 * DM, DM);
    // vT = transpose(V region)
    vtr_kernel<<<NBATCH * NHEADS * (SQ / 64), blk, 0, stream>>>(qkvb, vTb);
    // aob = softmax(q k^T) v
    fattn_mfma<<<NBATCH * NHEADS * (SQ / 64), blk, 0, stream>>>(qkvb, vTb, aob);
    // y = xn1 + aob @ wo^T + bo
    gemm_n64<0,1,0><<<dim3(DM / 64, NTOK / 128), blk, 0, stream>>>(
        aob, wob, bo, xnf, y, NTOK, DM, DM);
    // xn2 = LN2(y)
    ln_kernel<<<NTOK, blk, 0, stream>>>(y, g2, e2, xnf, xnb);
    // hb = gelu(xn2 @ w1^T + b1)   (bf16 out)
    gemm_bt<1,0,1><<<dim3(HM / 128, NTOK / 128), blk, 0, stream>>>(
        xnb, w1b, b1, nullptr, hb, NTOK, HM, DM);
    // out = xn2 + hb @ w2^T + b2   (fp32 out)
    gemm_n64<0,1,0><<<dim3(DM / 64, NTOK / 128), blk, 0, stream>>>(
        hb, w2b, b2, xnf, d_out, NTOK, DM, HM);
}